// Round 9
// baseline (376.118 us; speedup 1.0000x reference)
//
#include <hip/hip_runtime.h>
#include <math.h>

// Problem constants (fixed by setup_inputs)
#define M_SEG 128
#define S_SEG 512
#define HD 512
#define NHEAD 8
#define DHEAD 64
#define NROWS (M_SEG * S_SEG)   // 65536
#define QKVLD 1536              // fused qkv row stride
#define GAMMA_F 0.96875f
#define SCALE_F 0.125f          // d^-0.5

typedef unsigned short u16;
typedef float f32x4 __attribute__((ext_vector_type(4)));
typedef __bf16 bf16x8 __attribute__((ext_vector_type(8)));
typedef unsigned short ushort8 __attribute__((ext_vector_type(8)));
typedef unsigned short ushort4v __attribute__((ext_vector_type(4)));

__device__ __forceinline__ u16 f2bf(float f) {
    union { float f; unsigned u; } x; x.f = f;
    unsigned r = x.u + 0x7FFFu + ((x.u >> 16) & 1u);   // RNE
    return (u16)(r >> 16);
}
__device__ __forceinline__ float bf2f(u16 v) {
    union { unsigned u; float f; } x; x.u = ((unsigned)v) << 16;
    return x.f;
}

// Full compile-time fence: IR-level (memory clobber) + MIR scheduler (rule #18).
__device__ __forceinline__ void fence_all() {
    asm volatile("" ::: "memory");
    __builtin_amdgcn_sched_barrier(0);
}

// async global->LDS, 16B per lane; LDS dest = wave-uniform base + lane*16
__device__ __forceinline__ void gload16(const u16* g, u16* l) {
    __builtin_amdgcn_global_load_lds(
        (const __attribute__((address_space(1))) void*)g,
        (__attribute__((address_space(3))) void*)l, 16, 0, 0);
}

// ---------------------------------------------------------------------------
// fp32 -> bf16, 8 elems/thread
// ---------------------------------------------------------------------------
__global__ __launch_bounds__(256) void convert_bf16(const float* __restrict__ in,
                                                    u16* __restrict__ outp, int n8)
{
    int idx = blockIdx.x * 256 + threadIdx.x;
    if (idx >= n8) return;
    const float4 a = *reinterpret_cast<const float4*>(&in[(size_t)idx * 8]);
    const float4 b = *reinterpret_cast<const float4*>(&in[(size_t)idx * 8 + 4]);
    ushort8 o;
    o[0] = f2bf(a.x); o[1] = f2bf(a.y); o[2] = f2bf(a.z); o[3] = f2bf(a.w);
    o[4] = f2bf(b.x); o[5] = f2bf(b.y); o[6] = f2bf(b.z); o[7] = f2bf(b.w);
    *reinterpret_cast<ushort8*>(&outp[(size_t)idx * 8]) = o;
}

// 4 weights in one launch (blockIdx.y selects), each 512x512
__global__ __launch_bounds__(256) void convert_weights(const float* __restrict__ w0,
                                                       const float* __restrict__ w1,
                                                       const float* __restrict__ w2,
                                                       const float* __restrict__ w3,
                                                       u16* __restrict__ outp)
{
    const int which = blockIdx.y;
    const float* src = which == 0 ? w0 : which == 1 ? w1 : which == 2 ? w2 : w3;
    u16* dst = outp + (size_t)which * 262144;
    int idx = blockIdx.x * 256 + threadIdx.x;        // 32768 per weight
    const float4 a = *reinterpret_cast<const float4*>(&src[(size_t)idx * 8]);
    const float4 b = *reinterpret_cast<const float4*>(&src[(size_t)idx * 8 + 4]);
    ushort8 o;
    o[0] = f2bf(a.x); o[1] = f2bf(a.y); o[2] = f2bf(a.z); o[3] = f2bf(a.w);
    o[4] = f2bf(b.x); o[5] = f2bf(b.y); o[6] = f2bf(b.z); o[7] = f2bf(b.w);
    *reinterpret_cast<ushort8*>(&dst[(size_t)idx * 8]) = o;
}

// ---------------------------------------------------------------------------
// OCCUPANCY-FIRST 128x128 bf16 MFMA GEMM (NT), K=512, BK=32, 16 K-tiles.
// 256 thr / 4 waves (64x64 per wave), 2-buffer LDS = 32 KiB, 4 blocks/CU via
// __launch_bounds__(256,4) -> 16 waves/CU; TLP hides vmcnt + fill + epilogue.
// RACE FIX (R8 post-mortem): the 2-ring prefetch STAGE(kt+2) writes the SAME
// buffer read this iteration; a raw s_barrier has no compiler memory-fence
// semantics, so STAGE could hoist above it into the read region. fence_all()
// (memory clobber + sched_barrier(0)) after the end barrier pins it.
// Counted vmcnt(4) ledger: 4 loads/tile, prefetch distance 2.
// Swizzle both-sides: source k-slot = slot ^ ((row>>1)&3), linear gload
// dest, frag read applies the same XOR.
// EPI==0: C bf16 (ldc), coalesced via 32 KiB LDS pass.
// EPI==1: res = acc + X(fp32 msg) + bias -> bf16 at Cv (ldc), 2 half-passes.
// ---------------------------------------------------------------------------
template<int EPI>
__global__ __launch_bounds__(256, 4) void gemm4b(const u16* __restrict__ A, int lda,
                                                 const u16* __restrict__ B,
                                                 u16* __restrict__ Cv, int ldc, int ntile,
                                                 const float* __restrict__ Xf,
                                                 const float* __restrict__ bias)
{
    __shared__ __align__(16) u16 sm[2][8192];   // [buf][A 4096 | B 4096] = 32 KiB
    const int t    = threadIdx.x;
    const int lane = t & 63;
    const int w    = t >> 6;          // 4 waves
    const int wm   = w >> 1;          // 0..1 -> A 64-row half
    const int wn   = w & 1;           // 0..1 -> B 64-col half

    // XCD-bijective blockIdx swizzle (nwg % 8 == 0 in all uses here)
    const int nwg  = gridDim.x;
    const int cpx  = nwg >> 3;
    const int bid  = blockIdx.x;
    const int sbid = (bid & 7) * cpx + (bid >> 3);
    const int mt = sbid / ntile, nt = sbid % ntile;
    const int rowBase = mt * 128, colBase = nt * 128;

    const int frow = lane & 15, fkc = lane >> 4, orow = (lane >> 4) * 4;

    // staging: chunk t; rows sr0 (0..63) and sr0+64; source k-slot inverse-swz
    const int sr0 = t >> 2;
    const int ksl = (t & 3) ^ ((sr0 >> 1) & 3);    // (sr0+64)>>1 same &3

    const size_t gA0 = (size_t)(rowBase + sr0)      * lda + ksl * 8;
    const size_t gA1 = (size_t)(rowBase + sr0 + 64) * lda + ksl * 8;
    const size_t gB0 = (size_t)(colBase + sr0)      * HD  + ksl * 8;
    const size_t gB1 = (size_t)(colBase + sr0 + 64) * HD  + ksl * 8;

    f32x4 acc[4][4];
#pragma unroll
    for (int i = 0; i < 4; ++i)
#pragma unroll
        for (int j = 0; j < 4; ++j)
            acc[i][j] = (f32x4){0.f, 0.f, 0.f, 0.f};

#define STAGE(kt, buf)                                                        \
    do {                                                                      \
        gload16(&A[gA0 + (kt) * 32], &sm[buf][t * 8]);                        \
        gload16(&A[gA1 + (kt) * 32], &sm[buf][2048 + t * 8]);                 \
        gload16(&B[gB0 + (kt) * 32], &sm[buf][4096 + t * 8]);                 \
        gload16(&B[gB1 + (kt) * 32], &sm[buf][6144 + t * 8]);                 \
    } while (0)

    STAGE(0, 0);
    STAGE(1, 1);

#pragma unroll 1
    for (int kt = 0; kt < 16; ++kt) {
        const int buf = kt & 1;
        if (kt < 15) asm volatile("s_waitcnt vmcnt(4)" ::: "memory");
        else         asm volatile("s_waitcnt vmcnt(0)" ::: "memory");
        __builtin_amdgcn_s_barrier();
        fence_all();

        const u16* Ab = sm[buf];
        const u16* Bb = sm[buf] + 4096;
        bf16x8 af[4], bfv[4];
#pragma unroll
        for (int mm = 0; mm < 4; ++mm) {
            const int r = wm * 64 + mm * 16 + frow;
            af[mm] = *reinterpret_cast<const bf16x8*>(
                &Ab[r * 32 + ((fkc ^ ((r >> 1) & 3)) << 3)]);
        }
#pragma unroll
        for (int nn = 0; nn < 4; ++nn) {
            const int r = wn * 64 + nn * 16 + frow;
            bfv[nn] = *reinterpret_cast<const bf16x8*>(
                &Bb[r * 32 + ((fkc ^ ((r >> 1) & 3)) << 3)]);
        }
        __builtin_amdgcn_s_setprio(1);
#pragma unroll
        for (int mm = 0; mm < 4; ++mm)
#pragma unroll
            for (int nn = 0; nn < 4; ++nn)
                acc[mm][nn] = __builtin_amdgcn_mfma_f32_16x16x32_bf16(af[mm], bfv[nn], acc[mm][nn], 0, 0, 0);
        __builtin_amdgcn_s_setprio(0);

        __builtin_amdgcn_s_barrier();   // all waves done reading buf
        fence_all();                    // RACE FIX: pin STAGE below the barrier
        if (kt < 14) STAGE(kt + 2, buf);
    }
#undef STAGE

    if (EPI == 0) {
        // acc -> LDS (128x128 u16 = 32 KiB) -> coalesced ushort8 stores
        u16* ldsC = (u16*)sm;
#pragma unroll
        for (int mm = 0; mm < 4; ++mm)
#pragma unroll
            for (int nn = 0; nn < 4; ++nn) {
                const int row0 = wm * 64 + mm * 16 + orow;
                const int col  = wn * 64 + nn * 16 + frow;
#pragma unroll
                for (int r = 0; r < 4; ++r)
                    ldsC[(row0 + r) * 128 + col] = f2bf(acc[mm][nn][r]);
            }
        __syncthreads();
#pragma unroll
        for (int p = 0; p < 8; ++p) {
            const int lin = p * 256 + t;          // 2048 x 16B chunks
            const int row = lin >> 4, c8 = lin & 15;
            *reinterpret_cast<ushort8*>(
                &Cv[(size_t)(rowBase + row) * ldc + colBase + c8 * 8]) =
                *reinterpret_cast<const ushort8*>(&ldsC[row * 128 + c8 * 8]);
        }
    } else {
        // two half-passes of 64 rows: 64x128 f32 = 32 KiB; res=acc+X+bias->bf16
        float* ldsF = (float*)sm;
#pragma unroll
        for (int half = 0; half < 2; ++half) {
            __syncthreads();
            if (wm == half) {
#pragma unroll
                for (int mm = 0; mm < 4; ++mm)
#pragma unroll
                    for (int nn = 0; nn < 4; ++nn) {
                        const int row0 = mm * 16 + orow;          // 0..63 local
                        const int col  = wn * 64 + nn * 16 + frow;
#pragma unroll
                        for (int r = 0; r < 4; ++r)
                            ldsF[(row0 + r) * 128 + col] = acc[mm][nn][r];
                    }
            }
            __syncthreads();
#pragma unroll
            for (int p = 0; p < 8; ++p) {
                const int lin = p * 256 + t;      // 2048 float4 chunks
                const int row = lin >> 5, c4 = lin & 31;
                const int grow = rowBase + half * 64 + row;
                float4 a = *reinterpret_cast<const float4*>(&ldsF[row * 128 + c4 * 4]);
                float4 x = *reinterpret_cast<const float4*>(
                    &Xf[(size_t)grow * HD + colBase + c4 * 4]);
                float4 b = *reinterpret_cast<const float4*>(&bias[colBase + c4 * 4]);
                ushort4v o;
                o[0] = f2bf(a.x + x.x + b.x);
                o[1] = f2bf(a.y + x.y + b.y);
                o[2] = f2bf(a.z + x.z + b.z);
                o[3] = f2bf(a.w + x.w + b.w);
                *reinterpret_cast<ushort4v*>(
                    &Cv[(size_t)grow * ldc + colBase + c4 * 4]) = o;
            }
        }
    }
}

// ---------------------------------------------------------------------------
// MFMA KtV: A[m,h,d,e] = sum_s k[m,s,d] * v[m,s,e].
// RACE FIX: fence_all() after each end-of-compute barrier so the next WRTC's
// ds_writes (single-buffered kT/vT) cannot hoist above the barrier.
// ---------------------------------------------------------------------------
__global__ __launch_bounds__(256) void kv_outer_mfma(const u16* __restrict__ qkv,
                                                     float* __restrict__ Abuf)
{
    __shared__ __align__(16) u16 kT[2048];
    __shared__ __align__(16) u16 vT[2048];
    const int t    = threadIdx.x;
    const int lane = t & 63;
    const int w    = t >> 6;
    const int hh   = blockIdx.x;
    const int m    = blockIdx.y;
    const int sl   = t & 31;
    const int dg   = (t >> 5) * 8;
    const int frow = lane & 15, fkc = lane >> 4, orow = (lane >> 4) * 4;
    const size_t gbase = (size_t)(m * S_SEG) * QKVLD + 512 + hh * DHEAD + dg;

    f32x4 acc[4];
#pragma unroll
    for (int i = 0; i < 4; ++i) acc[i] = (f32x4){0.f, 0.f, 0.f, 0.f};

    ushort8 ka, va, kb, vb;

#define LOADC(c, K8, V8)                                                      \
    do {                                                                      \
        size_t g_ = gbase + (size_t)((c) * 32 + sl) * QKVLD;                  \
        K8 = *reinterpret_cast<const ushort8*>(&qkv[g_]);                     \
        V8 = *reinterpret_cast<const ushort8*>(&qkv[g_ + 512]);               \
    } while (0)
#define WRTC(K8, V8)                                                          \
    do {                                                                      \
        _Pragma("unroll")                                                     \
        for (int j = 0; j < 8; ++j) {                                         \
            const int d_ = dg + j;                                            \
            const int a_ = d_ * 32 + ((((sl >> 3) ^ ((d_ >> 1) & 3))) << 3) + (sl & 7); \
            kT[a_] = K8[j];                                                   \
            vT[a_] = V8[j];                                                   \
        }                                                                     \
    } while (0)
#define CMPC()                                                                \
    do {                                                                      \
        bf16x8 kf[4], vf;                                                     \
        _Pragma("unroll")                                                     \
        for (int mf = 0; mf < 4; ++mf) {                                      \
            const int d_ = mf * 16 + frow;                                    \
            kf[mf] = *reinterpret_cast<const bf16x8*>(                        \
                &kT[d_ * 32 + ((fkc ^ ((d_ >> 1) & 3)) << 3)]);               \
        }                                                                     \
        const int e_ = w * 16 + frow;                                         \
        vf = *reinterpret_cast<const bf16x8*>(                                \
            &vT[e_ * 32 + ((fkc ^ ((e_ >> 1) & 3)) << 3)]);                   \
        _Pragma("unroll")                                                     \
        for (int mf = 0; mf < 4; ++mf)                                        \
            acc[mf] = __builtin_amdgcn_mfma_f32_16x16x32_bf16(kf[mf], vf, acc[mf], 0, 0, 0); \
    } while (0)

    LOADC(0, ka, va);
#pragma unroll 1
    for (int cc = 0; cc < 16; cc += 2) {
        WRTC(ka, va);
        LOADC(cc + 1, kb, vb);
        asm volatile("s_waitcnt lgkmcnt(0)" ::: "memory");
        __builtin_amdgcn_s_barrier();
        __builtin_amdgcn_sched_barrier(0);
        CMPC();
        __builtin_amdgcn_s_barrier();
        fence_all();                    // RACE FIX

        WRTC(kb, vb);
        if (cc + 2 < 16) LOADC(cc + 2, ka, va);
        asm volatile("s_waitcnt lgkmcnt(0)" ::: "memory");
        __builtin_amdgcn_s_barrier();
        __builtin_amdgcn_sched_barrier(0);
        CMPC();
        __builtin_amdgcn_s_barrier();
        fence_all();                    // RACE FIX
    }
#undef LOADC
#undef WRTC
#undef CMPC

    const size_t hb = (size_t)(m * NHEAD + hh) * DHEAD * DHEAD;
#pragma unroll
    for (int mf = 0; mf < 4; ++mf)
#pragma unroll
        for (int r = 0; r < 4; ++r)
            Abuf[hb + (size_t)(mf * 16 + orow + r) * DHEAD + w * 16 + frow] = acc[mf][r];
}

// ---------------------------------------------------------------------------
// r_m = A_m + decay*r_{m-1} ;  Bc_m = scale*A_m + gamma^{m+1} * r_m  (fp32)
// ---------------------------------------------------------------------------
__global__ __launch_bounds__(256) void scan_kernel(const float* __restrict__ Abuf,
                                                   float* __restrict__ Bc)
{
    const int tid = blockIdx.x * 256 + threadIdx.x;   // 0..32767
    const float decay = powf(GAMMA_F, (float)S_SEG);
    float r = 0.0f;
    float g = 1.0f;
    for (int m = 0; m < M_SEG; ++m) {
        float a = Abuf[(size_t)m * 32768 + tid];
        r = fmaf(decay, r, a);
        g *= GAMMA_F;
        Bc[(size_t)m * 32768 + tid] = fmaf(g, r, SCALE_F * a);
    }
}

// ---------------------------------------------------------------------------
// h = relu(q @ Bc) IN PLACE into qkv's q-slot. NUMERIC MARGIN: Bc is split
// into bf16 hi+lo (lo = Bc - hi); two MFMA chains recover near-fp32 Bc
// precision on the dominant cross term (lo product added first).
// ---------------------------------------------------------------------------
__global__ __launch_bounds__(256) void h_mfma(u16* __restrict__ qkv,
                                              const float* __restrict__ Bc)
{
    __shared__ __align__(16) u16 BTh[64 * 72];   // hi [e][d], pad 72
    __shared__ __align__(16) u16 BTl[64 * 72];   // lo [e][d]
    const int t    = threadIdx.x;
    const int lane = t & 63;
    const int w    = t >> 6;
    const int m    = blockIdx.y;
    const int sBase = blockIdx.x * 256 + w * 64;
    const int frow = lane & 15;
    const int fkc  = lane >> 4;

    for (int hh = 0; hh < NHEAD; ++hh) {
#pragma unroll
        for (int i = 0; i < 4; ++i) {
            int idx = t + i * 256;               // 1024 float4s
            int d = idx >> 4, e4 = idx & 15;
            float4 v = *reinterpret_cast<const float4*>(
                &Bc[((size_t)(m * NHEAD + hh) * DHEAD + d) * DHEAD + e4 * 4]);
            float vv[4] = {v.x, v.y, v.z, v.w};
#pragma unroll
            for (int j = 0; j < 4; ++j) {
                u16 hi = f2bf(vv[j]);
                BTh[(e4 * 4 + j) * 72 + d] = hi;
                BTl[(e4 * 4 + j) * 72 + d] = f2bf(vv[j] - bf2f(hi));
            }
        }
        __syncthreads();

        f32x4 acc[4][4];
#pragma unroll
        for (int i = 0; i < 4; ++i)
#pragma unroll
            for (int j = 0; j < 4; ++j)
                acc[i][j] = (f32x4){0.f, 0.f, 0.f, 0.f};

#pragma unroll
        for (int ks = 0; ks < 2; ++ks) {
            bf16x8 af[4], bh[4], bl[4];
#pragma unroll
            for (int mm = 0; mm < 4; ++mm) {
                const int grow = m * S_SEG + sBase + mm * 16 + frow;
                af[mm] = *reinterpret_cast<const bf16x8*>(
                    &qkv[(size_t)grow * QKVLD + hh * DHEAD + ks * 32 + fkc * 8]);
                const int e = mm * 16 + frow;
                bh[mm] = *reinterpret_cast<const bf16x8*>(&BTh[e * 72 + ks * 32 + fkc * 8]);
                bl[mm] = *reinterpret_cast<const bf16x8*>(&BTl[e * 72 + ks * 32 + fkc * 8]);
            }
#pragma unroll
            for (int mm = 0; mm < 4; ++mm)
#pragma unroll
                for (int nn = 0; nn < 4; ++nn) {
                    acc[mm][nn] = __builtin_amdgcn_mfma_f32_16x16x32_bf16(af[mm], bl[nn], acc[mm][nn], 0, 0, 0);
                    acc[mm][nn] = __builtin_amdgcn_mfma_f32_16x16x32_bf16(af[mm], bh[nn], acc[mm][nn], 0, 0, 0);
                }
        }

        const int orow = (lane >> 4) * 4;
#pragma unroll
        for (int mm = 0; mm < 4; ++mm)
#pragma unroll
            for (int nn = 0; nn < 4; ++nn) {
                const int col  = hh * DHEAD + nn * 16 + frow;
                const int row0 = m * S_SEG + sBase + mm * 16 + orow;
#pragma unroll
                for (int r = 0; r < 4; ++r)
                    qkv[(size_t)(row0 + r) * QKVLD + col] = f2bf(fmaxf(acc[mm][nn][r], 0.f));
            }
        __syncthreads();
    }
}

// ---------------------------------------------------------------------------
// GroupNorm from bf16 res (qkv k-slot, stride 1536) -> fp32 d_out rows 1..N
// ---------------------------------------------------------------------------
__global__ __launch_bounds__(256) void groupnorm_bf16(const u16* __restrict__ res,
                                                      float* __restrict__ out,
                                                      const float* __restrict__ gn_w,
                                                      const float* __restrict__ gn_b)
{
    const int g = blockIdx.x;
    const int m = blockIdx.y;
    const int t = threadIdx.x;
    const u16* base = res + (size_t)(m * S_SEG) * QKVLD + g * DHEAD;

    float sum = 0.0f, sq = 0.0f;
    for (int idx = t; idx < 4096; idx += 256) {      // 512 rows x 8 ushort8
        int s = idx >> 3, c8 = idx & 7;
        ushort8 v = *reinterpret_cast<const ushort8*>(&base[(size_t)s * QKVLD + c8 * 8]);
#pragma unroll
        for (int j = 0; j < 8; ++j) {
            float f = bf2f(v[j]);
            sum += f; sq += f * f;
        }
    }
    __shared__ float rs[256], rq[256];
    rs[t] = sum; rq[t] = sq;
    __syncthreads();
    for (int off = 128; off > 0; off >>= 1) {
        if (t < off) { rs[t] += rs[t + off]; rq[t] += rq[t + off]; }
        __syncthreads();
    }
    __shared__ float smean, sinv;
    if (t == 0) {
        float mean = rs[0] * (1.0f / 32768.0f);
        float var  = rq[0] * (1.0f / 32768.0f) - mean * mean;
        smean = mean;
        sinv  = rsqrtf(var + 1e-5f);
    }
    __syncthreads();
    const float mean = smean, inv = sinv;

    for (int idx = t; idx < 4096; idx += 256) {
        int s = idx >> 3, c8 = idx & 7;
        ushort8 v = *reinterpret_cast<const ushort8*>(&base[(size_t)s * QKVLD + c8 * 8]);
        float o[8];
#pragma unroll
        for (int j = 0; j < 8; ++j) {
            float wj = gn_w[g * DHEAD + c8 * 8 + j];
            float bj = gn_b[g * DHEAD + c8 * 8 + j];
            o[j] = (bf2f(v[j]) - mean) * inv * wj + bj;
        }
        float* dst = &out[(size_t)(1 + m * S_SEG + s) * HD + g * DHEAD + c8 * 8];
        *reinterpret_cast<float4*>(dst)     = make_float4(o[0], o[1], o[2], o[3]);
        *reinterpret_cast<float4*>(dst + 4) = make_float4(o[4], o[5], o[6], o[7]);
    }
}

__global__ void zero_row(float* __restrict__ out)
{
    int i = blockIdx.x * 256 + threadIdx.x;
    if (i < HD) out[i] = 0.0f;
}

// ---------------------------------------------------------------------------
extern "C" void kernel_launch(void* const* d_in, const int* in_sizes, int n_in,
                              void* d_out, int out_size, void* d_ws, size_t ws_size,
                              hipStream_t stream)
{
    const float* msg = (const float*)d_in[0];
    const float* Wq  = (const float*)d_in[1];
    const float* Wk  = (const float*)d_in[2];
    const float* Wv  = (const float*)d_in[3];
    const float* Wo  = (const float*)d_in[4];
    const float* bo  = (const float*)d_in[5];
    const float* gnw = (const float*)d_in[6];
    const float* gnb = (const float*)d_in[7];
    float* out = (float*)d_out;

    // d_out scratch (consumed before groupnorm rewrites d_out):
    //   msgb bf16 (67.1 MB) | Abuf fp32 (16.8 MB) | Bc fp32 (16.8 MB)
    u16*   msgb = (u16*)out;
    float* Abuf = out + 16777216;
    float* Bc   = out + 16777216 + 4194304;

    // d_ws: Wb 2 MB (Wq|Wk|Wv|Wo bf16) + qkv 201.3 MB (65536 x 1536).
    // h_mfma overwrites qkv's q-slot with h; EPI gemm writes bf16 res into
    // qkv's k-slot (dead after kv_outer_mfma).
    u16* Wb   = (u16*)d_ws;
    u16* qkv  = Wb + 4 * 262144;
    u16* resB = qkv + 512;    // res bf16, stride 1536

    convert_weights<<<dim3(128, 4), 256, 0, stream>>>(Wq, Wk, Wv, Wo, Wb);
    convert_bf16<<<16384, 256, 0, stream>>>(msg, msgb, 4194304);

    // fused QKV GEMM: A=msgb (65536x512), B=[Wq;Wk;Wv] (1536x512) -> qkv
    // 512 row-tiles x 12 col-tiles = 6144 blocks (%8==0)
    gemm4b<0><<<6144, 256, 0, stream>>>(msgb, HD, Wb, qkv, QKVLD, 12, nullptr, nullptr);

    kv_outer_mfma<<<dim3(NHEAD, M_SEG), 256, 0, stream>>>(qkv, Abuf);
    scan_kernel<<<128, 256, 0, stream>>>(Abuf, Bc);
    h_mfma<<<dim3(2, M_SEG), 256, 0, stream>>>(qkv, Bc);

    // output GEMM: A=h (qkv q-slot, lda=1536), B=Wo; res=acc+msg(fp32)+bias
    // 512 row-tiles x 4 col-tiles = 2048 blocks (%8==0)
    gemm4b<1><<<2048, 256, 0, stream>>>(qkv, QKVLD, Wb + 3 * 262144, resB, QKVLD, 4, msg, bo);

    zero_row<<<2, 256, 0, stream>>>(out);
    groupnorm_bf16<<<dim3(8, M_SEG), 256, 0, stream>>>(resB, out, gnw, gnb);
}

// Round 10
// 374.320 us; speedup vs baseline: 1.0048x; 1.0048x over previous
//
#include <hip/hip_runtime.h>
#include <math.h>

// Problem constants (fixed by setup_inputs)
#define M_SEG 128
#define S_SEG 512
#define HD 512
#define NHEAD 8
#define DHEAD 64
#define NROWS (M_SEG * S_SEG)   // 65536
#define QKVLD 1536              // fused qkv row stride
#define GAMMA_F 0.96875f
#define SCALE_F 0.125f          // d^-0.5

typedef unsigned short u16;
typedef float f32x4 __attribute__((ext_vector_type(4)));
typedef __bf16 bf16x8 __attribute__((ext_vector_type(8)));
typedef unsigned short ushort8 __attribute__((ext_vector_type(8)));
typedef unsigned short ushort4v __attribute__((ext_vector_type(4)));

__device__ __forceinline__ u16 f2bf(float f) {
    union { float f; unsigned u; } x; x.f = f;
    unsigned r = x.u + 0x7FFFu + ((x.u >> 16) & 1u);   // RNE
    return (u16)(r >> 16);
}
__device__ __forceinline__ float bf2f(u16 v) {
    union { unsigned u; float f; } x; x.u = ((unsigned)v) << 16;
    return x.f;
}

// Full compile-time fence: IR-level (memory clobber) + MIR scheduler (rule #18).
__device__ __forceinline__ void fence_all() {
    asm volatile("" ::: "memory");
    __builtin_amdgcn_sched_barrier(0);
}

// async global->LDS, 16B per lane; LDS dest = wave-uniform base + lane*16
__device__ __forceinline__ void gload16(const u16* g, u16* l) {
    __builtin_amdgcn_global_load_lds(
        (const __attribute__((address_space(1))) void*)g,
        (__attribute__((address_space(3))) void*)l, 16, 0, 0);
}

// ---------------------------------------------------------------------------
// fp32 -> bf16, 8 elems/thread
// ---------------------------------------------------------------------------
__global__ __launch_bounds__(256) void convert_bf16(const float* __restrict__ in,
                                                    u16* __restrict__ outp, int n8)
{
    int idx = blockIdx.x * 256 + threadIdx.x;
    if (idx >= n8) return;
    const float4 a = *reinterpret_cast<const float4*>(&in[(size_t)idx * 8]);
    const float4 b = *reinterpret_cast<const float4*>(&in[(size_t)idx * 8 + 4]);
    ushort8 o;
    o[0] = f2bf(a.x); o[1] = f2bf(a.y); o[2] = f2bf(a.z); o[3] = f2bf(a.w);
    o[4] = f2bf(b.x); o[5] = f2bf(b.y); o[6] = f2bf(b.z); o[7] = f2bf(b.w);
    *reinterpret_cast<ushort8*>(&outp[(size_t)idx * 8]) = o;
}

// 4 weights in one launch (blockIdx.y selects), each 512x512
__global__ __launch_bounds__(256) void convert_weights(const float* __restrict__ w0,
                                                       const float* __restrict__ w1,
                                                       const float* __restrict__ w2,
                                                       const float* __restrict__ w3,
                                                       u16* __restrict__ outp)
{
    const int which = blockIdx.y;
    const float* src = which == 0 ? w0 : which == 1 ? w1 : which == 2 ? w2 : w3;
    u16* dst = outp + (size_t)which * 262144;
    int idx = blockIdx.x * 256 + threadIdx.x;        // 32768 per weight
    const float4 a = *reinterpret_cast<const float4*>(&src[(size_t)idx * 8]);
    const float4 b = *reinterpret_cast<const float4*>(&src[(size_t)idx * 8 + 4]);
    ushort8 o;
    o[0] = f2bf(a.x); o[1] = f2bf(a.y); o[2] = f2bf(a.z); o[3] = f2bf(a.w);
    o[4] = f2bf(b.x); o[5] = f2bf(b.y); o[6] = f2bf(b.z); o[7] = f2bf(b.w);
    *reinterpret_cast<ushort8*>(&dst[(size_t)idx * 8]) = o;
}

// ---------------------------------------------------------------------------
// OCCUPANCY-FIRST 128x128 bf16 MFMA GEMM (NT), K=512, BK=32, 16 K-tiles.
// 256 thr / 4 waves (64x64 per wave), 2-buffer LDS = 32 KiB, ~3-4 blocks/CU.
// R9 diagnosis: LDS-read-port bound at ~0.03 B/FLOP -> MfmaUtil plateaus
// ~33% regardless of schedule; this structure is kept as the plateau-best.
// Race-safe: fence_all() (memory clobber + sched_barrier) pins the 2-ring
// prefetch STAGE below the end barrier (R8 post-mortem).
// Counted vmcnt(4): 4 loads/tile, prefetch distance 2.
// Swizzle both-sides: source k-slot = slot ^ ((row>>1)&3), linear gload
// dest, frag read applies the same XOR.
// EPI==0: C bf16 (ldc), coalesced via 32 KiB LDS pass.
// EPI==1: res = acc + X(bf16 msgb) + bias -> bf16 at Cv (ldc), 2 half-passes.
// ---------------------------------------------------------------------------
template<int EPI>
__global__ __launch_bounds__(256, 4) void gemm4b(const u16* __restrict__ A, int lda,
                                                 const u16* __restrict__ B,
                                                 u16* __restrict__ Cv, int ldc, int ntile,
                                                 const u16* __restrict__ Xb,
                                                 const float* __restrict__ bias)
{
    __shared__ __align__(16) u16 sm[2][8192];   // [buf][A 4096 | B 4096] = 32 KiB
    const int t    = threadIdx.x;
    const int lane = t & 63;
    const int w    = t >> 6;          // 4 waves
    const int wm   = w >> 1;          // 0..1 -> A 64-row half
    const int wn   = w & 1;           // 0..1 -> B 64-col half

    // XCD-bijective blockIdx swizzle (nwg % 8 == 0 in all uses here)
    const int nwg  = gridDim.x;
    const int cpx  = nwg >> 3;
    const int bid  = blockIdx.x;
    const int sbid = (bid & 7) * cpx + (bid >> 3);
    const int mt = sbid / ntile, nt = sbid % ntile;
    const int rowBase = mt * 128, colBase = nt * 128;

    const int frow = lane & 15, fkc = lane >> 4, orow = (lane >> 4) * 4;

    // staging: chunk t; rows sr0 (0..63) and sr0+64; source k-slot inverse-swz
    const int sr0 = t >> 2;
    const int ksl = (t & 3) ^ ((sr0 >> 1) & 3);    // (sr0+64)>>1 same &3

    const size_t gA0 = (size_t)(rowBase + sr0)      * lda + ksl * 8;
    const size_t gA1 = (size_t)(rowBase + sr0 + 64) * lda + ksl * 8;
    const size_t gB0 = (size_t)(colBase + sr0)      * HD  + ksl * 8;
    const size_t gB1 = (size_t)(colBase + sr0 + 64) * HD  + ksl * 8;

    f32x4 acc[4][4];
#pragma unroll
    for (int i = 0; i < 4; ++i)
#pragma unroll
        for (int j = 0; j < 4; ++j)
            acc[i][j] = (f32x4){0.f, 0.f, 0.f, 0.f};

#define STAGE(kt, buf)                                                        \
    do {                                                                      \
        gload16(&A[gA0 + (kt) * 32], &sm[buf][t * 8]);                        \
        gload16(&A[gA1 + (kt) * 32], &sm[buf][2048 + t * 8]);                 \
        gload16(&B[gB0 + (kt) * 32], &sm[buf][4096 + t * 8]);                 \
        gload16(&B[gB1 + (kt) * 32], &sm[buf][6144 + t * 8]);                 \
    } while (0)

    STAGE(0, 0);
    STAGE(1, 1);

#pragma unroll 1
    for (int kt = 0; kt < 16; ++kt) {
        const int buf = kt & 1;
        if (kt < 15) asm volatile("s_waitcnt vmcnt(4)" ::: "memory");
        else         asm volatile("s_waitcnt vmcnt(0)" ::: "memory");
        __builtin_amdgcn_s_barrier();
        fence_all();

        const u16* Ab = sm[buf];
        const u16* Bb = sm[buf] + 4096;
        bf16x8 af[4], bfv[4];
#pragma unroll
        for (int mm = 0; mm < 4; ++mm) {
            const int r = wm * 64 + mm * 16 + frow;
            af[mm] = *reinterpret_cast<const bf16x8*>(
                &Ab[r * 32 + ((fkc ^ ((r >> 1) & 3)) << 3)]);
        }
#pragma unroll
        for (int nn = 0; nn < 4; ++nn) {
            const int r = wn * 64 + nn * 16 + frow;
            bfv[nn] = *reinterpret_cast<const bf16x8*>(
                &Bb[r * 32 + ((fkc ^ ((r >> 1) & 3)) << 3)]);
        }
        __builtin_amdgcn_s_setprio(1);
#pragma unroll
        for (int mm = 0; mm < 4; ++mm)
#pragma unroll
            for (int nn = 0; nn < 4; ++nn)
                acc[mm][nn] = __builtin_amdgcn_mfma_f32_16x16x32_bf16(af[mm], bfv[nn], acc[mm][nn], 0, 0, 0);
        __builtin_amdgcn_s_setprio(0);

        __builtin_amdgcn_s_barrier();   // all waves done reading buf
        fence_all();                    // pin STAGE below the barrier
        if (kt < 14) STAGE(kt + 2, buf);
    }
#undef STAGE

    if (EPI == 0) {
        // acc -> LDS (128x128 u16 = 32 KiB) -> coalesced ushort8 stores
        u16* ldsC = (u16*)sm;
#pragma unroll
        for (int mm = 0; mm < 4; ++mm)
#pragma unroll
            for (int nn = 0; nn < 4; ++nn) {
                const int row0 = wm * 64 + mm * 16 + orow;
                const int col  = wn * 64 + nn * 16 + frow;
#pragma unroll
                for (int r = 0; r < 4; ++r)
                    ldsC[(row0 + r) * 128 + col] = f2bf(acc[mm][nn][r]);
            }
        __syncthreads();
#pragma unroll
        for (int p = 0; p < 8; ++p) {
            const int lin = p * 256 + t;          // 2048 x 16B chunks
            const int row = lin >> 4, c8 = lin & 15;
            *reinterpret_cast<ushort8*>(
                &Cv[(size_t)(rowBase + row) * ldc + colBase + c8 * 8]) =
                *reinterpret_cast<const ushort8*>(&ldsC[row * 128 + c8 * 8]);
        }
    } else {
        // two half-passes of 64 rows: 64x128 f32 = 32 KiB; res=acc+X+bias->bf16
        float* ldsF = (float*)sm;
#pragma unroll
        for (int half = 0; half < 2; ++half) {
            __syncthreads();
            if (wm == half) {
#pragma unroll
                for (int mm = 0; mm < 4; ++mm)
#pragma unroll
                    for (int nn = 0; nn < 4; ++nn) {
                        const int row0 = mm * 16 + orow;          // 0..63 local
                        const int col  = wn * 64 + nn * 16 + frow;
#pragma unroll
                        for (int r = 0; r < 4; ++r)
                            ldsF[(row0 + r) * 128 + col] = acc[mm][nn][r];
                    }
            }
            __syncthreads();
#pragma unroll
            for (int p = 0; p < 8; ++p) {
                const int lin = p * 256 + t;      // 2048 float4 chunks
                const int row = lin >> 5, c4 = lin & 31;
                const int grow = rowBase + half * 64 + row;
                float4 a = *reinterpret_cast<const float4*>(&ldsF[row * 128 + c4 * 4]);
                ushort4v x4 = *reinterpret_cast<const ushort4v*>(
                    &Xb[(size_t)grow * HD + colBase + c4 * 4]);
                float4 b = *reinterpret_cast<const float4*>(&bias[colBase + c4 * 4]);
                ushort4v o;
                o[0] = f2bf(a.x + bf2f(x4[0]) + b.x);
                o[1] = f2bf(a.y + bf2f(x4[1]) + b.y);
                o[2] = f2bf(a.z + bf2f(x4[2]) + b.z);
                o[3] = f2bf(a.w + bf2f(x4[3]) + b.w);
                *reinterpret_cast<ushort4v*>(
                    &Cv[(size_t)grow * ldc + colBase + c4 * 4]) = o;
            }
        }
    }
}

// ---------------------------------------------------------------------------
// MFMA KtV: A[m,h,d,e] = sum_s k[m,s,d] * v[m,s,e].  Race-safe (fence_all
// after each end-of-compute barrier; single-buffered kT/vT).
// ---------------------------------------------------------------------------
__global__ __launch_bounds__(256) void kv_outer_mfma(const u16* __restrict__ qkv,
                                                     float* __restrict__ Abuf)
{
    __shared__ __align__(16) u16 kT[2048];
    __shared__ __align__(16) u16 vT[2048];
    const int t    = threadIdx.x;
    const int lane = t & 63;
    const int w    = t >> 6;
    const int hh   = blockIdx.x;
    const int m    = blockIdx.y;
    const int sl   = t & 31;
    const int dg   = (t >> 5) * 8;
    const int frow = lane & 15, fkc = lane >> 4, orow = (lane >> 4) * 4;
    const size_t gbase = (size_t)(m * S_SEG) * QKVLD + 512 + hh * DHEAD + dg;

    f32x4 acc[4];
#pragma unroll
    for (int i = 0; i < 4; ++i) acc[i] = (f32x4){0.f, 0.f, 0.f, 0.f};

    ushort8 ka, va, kb, vb;

#define LOADC(c, K8, V8)                                                      \
    do {                                                                      \
        size_t g_ = gbase + (size_t)((c) * 32 + sl) * QKVLD;                  \
        K8 = *reinterpret_cast<const ushort8*>(&qkv[g_]);                     \
        V8 = *reinterpret_cast<const ushort8*>(&qkv[g_ + 512]);               \
    } while (0)
#define WRTC(K8, V8)                                                          \
    do {                                                                      \
        _Pragma("unroll")                                                     \
        for (int j = 0; j < 8; ++j) {                                         \
            const int d_ = dg + j;                                            \
            const int a_ = d_ * 32 + ((((sl >> 3) ^ ((d_ >> 1) & 3))) << 3) + (sl & 7); \
            kT[a_] = K8[j];                                                   \
            vT[a_] = V8[j];                                                   \
        }                                                                     \
    } while (0)
#define CMPC()                                                                \
    do {                                                                      \
        bf16x8 kf[4], vf;                                                     \
        _Pragma("unroll")                                                     \
        for (int mf = 0; mf < 4; ++mf) {                                      \
            const int d_ = mf * 16 + frow;                                    \
            kf[mf] = *reinterpret_cast<const bf16x8*>(                        \
                &kT[d_ * 32 + ((fkc ^ ((d_ >> 1) & 3)) << 3)]);               \
        }                                                                     \
        const int e_ = w * 16 + frow;                                         \
        vf = *reinterpret_cast<const bf16x8*>(                                \
            &vT[e_ * 32 + ((fkc ^ ((e_ >> 1) & 3)) << 3)]);                   \
        _Pragma("unroll")                                                     \
        for (int mf = 0; mf < 4; ++mf)                                        \
            acc[mf] = __builtin_amdgcn_mfma_f32_16x16x32_bf16(kf[mf], vf, acc[mf], 0, 0, 0); \
    } while (0)

    LOADC(0, ka, va);
#pragma unroll 1
    for (int cc = 0; cc < 16; cc += 2) {
        WRTC(ka, va);
        LOADC(cc + 1, kb, vb);
        asm volatile("s_waitcnt lgkmcnt(0)" ::: "memory");
        __builtin_amdgcn_s_barrier();
        __builtin_amdgcn_sched_barrier(0);
        CMPC();
        __builtin_amdgcn_s_barrier();
        fence_all();

        WRTC(kb, vb);
        if (cc + 2 < 16) LOADC(cc + 2, ka, va);
        asm volatile("s_waitcnt lgkmcnt(0)" ::: "memory");
        __builtin_amdgcn_s_barrier();
        __builtin_amdgcn_sched_barrier(0);
        CMPC();
        __builtin_amdgcn_s_barrier();
        fence_all();
    }
#undef LOADC
#undef WRTC
#undef CMPC

    const size_t hb = (size_t)(m * NHEAD + hh) * DHEAD * DHEAD;
#pragma unroll
    for (int mf = 0; mf < 4; ++mf)
#pragma unroll
        for (int r = 0; r < 4; ++r)
            Abuf[hb + (size_t)(mf * 16 + orow + r) * DHEAD + w * 16 + frow] = acc[mf][r];
}

// ---------------------------------------------------------------------------
// r_m = A_m + decay*r_{m-1} ;  Bc_m = scale*A_m + gamma^{m+1} * r_m  (fp32)
// ---------------------------------------------------------------------------
__global__ __launch_bounds__(256) void scan_kernel(const float* __restrict__ Abuf,
                                                   float* __restrict__ Bc)
{
    const int tid = blockIdx.x * 256 + threadIdx.x;   // 0..32767
    const float decay = powf(GAMMA_F, (float)S_SEG);
    float r = 0.0f;
    float g = 1.0f;
    for (int m = 0; m < M_SEG; ++m) {
        float a = Abuf[(size_t)m * 32768 + tid];
        r = fmaf(decay, r, a);
        g *= GAMMA_F;
        Bc[(size_t)m * 32768 + tid] = fmaf(g, r, SCALE_F * a);
    }
}

// ---------------------------------------------------------------------------
// h = relu(q @ Bc) IN PLACE into qkv's q-slot. Plain bf16 Bc (hi/lo split
// reverted: R9 absmax 0.0469 == R5's 0.047 without it -> error budget is
// dominated by bf16 h/qkv, the split bought nothing for 2x MFMA cost).
// ---------------------------------------------------------------------------
__global__ __launch_bounds__(256) void h_mfma(u16* __restrict__ qkv,
                                              const float* __restrict__ Bc)
{
    __shared__ __align__(16) u16 BT[64 * 72];    // Bc^T [e][d], pad 72
    const int t    = threadIdx.x;
    const int lane = t & 63;
    const int w    = t >> 6;
    const int m    = blockIdx.y;
    const int sBase = blockIdx.x * 256 + w * 64;
    const int frow = lane & 15;
    const int fkc  = lane >> 4;

    for (int hh = 0; hh < NHEAD; ++hh) {
#pragma unroll
        for (int i = 0; i < 4; ++i) {
            int idx = t + i * 256;               // 1024 float4s
            int d = idx >> 4, e4 = idx & 15;
            float4 v = *reinterpret_cast<const float4*>(
                &Bc[((size_t)(m * NHEAD + hh) * DHEAD + d) * DHEAD + e4 * 4]);
            BT[(e4 * 4 + 0) * 72 + d] = f2bf(v.x);
            BT[(e4 * 4 + 1) * 72 + d] = f2bf(v.y);
            BT[(e4 * 4 + 2) * 72 + d] = f2bf(v.z);
            BT[(e4 * 4 + 3) * 72 + d] = f2bf(v.w);
        }
        __syncthreads();

        f32x4 acc[4][4];
#pragma unroll
        for (int i = 0; i < 4; ++i)
#pragma unroll
            for (int j = 0; j < 4; ++j)
                acc[i][j] = (f32x4){0.f, 0.f, 0.f, 0.f};

#pragma unroll
        for (int ks = 0; ks < 2; ++ks) {
            bf16x8 af[4], bfr[4];
#pragma unroll
            for (int mm = 0; mm < 4; ++mm) {
                const int grow = m * S_SEG + sBase + mm * 16 + frow;
                af[mm] = *reinterpret_cast<const bf16x8*>(
                    &qkv[(size_t)grow * QKVLD + hh * DHEAD + ks * 32 + fkc * 8]);
                const int e = mm * 16 + frow;
                bfr[mm] = *reinterpret_cast<const bf16x8*>(&BT[e * 72 + ks * 32 + fkc * 8]);
            }
#pragma unroll
            for (int mm = 0; mm < 4; ++mm)
#pragma unroll
                for (int nn = 0; nn < 4; ++nn)
                    acc[mm][nn] = __builtin_amdgcn_mfma_f32_16x16x32_bf16(af[mm], bfr[nn], acc[mm][nn], 0, 0, 0);
        }

        const int orow = (lane >> 4) * 4;
#pragma unroll
        for (int mm = 0; mm < 4; ++mm)
#pragma unroll
            for (int nn = 0; nn < 4; ++nn) {
                const int col  = hh * DHEAD + nn * 16 + frow;
                const int row0 = m * S_SEG + sBase + mm * 16 + orow;
#pragma unroll
                for (int r = 0; r < 4; ++r)
                    qkv[(size_t)(row0 + r) * QKVLD + col] = f2bf(fmaxf(acc[mm][nn][r], 0.f));
            }
        __syncthreads();
    }
}

// ---------------------------------------------------------------------------
// GroupNorm from bf16 res (qkv k-slot, stride 1536) -> fp32 d_out rows 1..N
// ---------------------------------------------------------------------------
__global__ __launch_bounds__(256) void groupnorm_bf16(const u16* __restrict__ res,
                                                      float* __restrict__ out,
                                                      const float* __restrict__ gn_w,
                                                      const float* __restrict__ gn_b)
{
    const int g = blockIdx.x;
    const int m = blockIdx.y;
    const int t = threadIdx.x;
    const u16* base = res + (size_t)(m * S_SEG) * QKVLD + g * DHEAD;

    float sum = 0.0f, sq = 0.0f;
    for (int idx = t; idx < 4096; idx += 256) {      // 512 rows x 8 ushort8
        int s = idx >> 3, c8 = idx & 7;
        ushort8 v = *reinterpret_cast<const ushort8*>(&base[(size_t)s * QKVLD + c8 * 8]);
#pragma unroll
        for (int j = 0; j < 8; ++j) {
            float f = bf2f(v[j]);
            sum += f; sq += f * f;
        }
    }
    __shared__ float rs[256], rq[256];
    rs[t] = sum; rq[t] = sq;
    __syncthreads();
    for (int off = 128; off > 0; off >>= 1) {
        if (t < off) { rs[t] += rs[t + off]; rq[t] += rq[t + off]; }
        __syncthreads();
    }
    __shared__ float smean, sinv;
    if (t == 0) {
        float mean = rs[0] * (1.0f / 32768.0f);
        float var  = rq[0] * (1.0f / 32768.0f) - mean * mean;
        smean = mean;
        sinv  = rsqrtf(var + 1e-5f);
    }
    __syncthreads();
    const float mean = smean, inv = sinv;

    for (int idx = t; idx < 4096; idx += 256) {
        int s = idx >> 3, c8 = idx & 7;
        ushort8 v = *reinterpret_cast<const ushort8*>(&base[(size_t)s * QKVLD + c8 * 8]);
        float o[8];
#pragma unroll
        for (int j = 0; j < 8; ++j) {
            float wj = gn_w[g * DHEAD + c8 * 8 + j];
            float bj = gn_b[g * DHEAD + c8 * 8 + j];
            o[j] = (bf2f(v[j]) - mean) * inv * wj + bj;
        }
        float* dst = &out[(size_t)(1 + m * S_SEG + s) * HD + g * DHEAD + c8 * 8];
        *reinterpret_cast<float4*>(dst)     = make_float4(o[0], o[1], o[2], o[3]);
        *reinterpret_cast<float4*>(dst + 4) = make_float4(o[4], o[5], o[6], o[7]);
    }
}

__global__ void zero_row(float* __restrict__ out)
{
    int i = blockIdx.x * 256 + threadIdx.x;
    if (i < HD) out[i] = 0.0f;
}

// ---------------------------------------------------------------------------
extern "C" void kernel_launch(void* const* d_in, const int* in_sizes, int n_in,
                              void* d_out, int out_size, void* d_ws, size_t ws_size,
                              hipStream_t stream)
{
    const float* msg = (const float*)d_in[0];
    const float* Wq  = (const float*)d_in[1];
    const float* Wk  = (const float*)d_in[2];
    const float* Wv  = (const float*)d_in[3];
    const float* Wo  = (const float*)d_in[4];
    const float* bo  = (const float*)d_in[5];
    const float* gnw = (const float*)d_in[6];
    const float* gnb = (const float*)d_in[7];
    float* out = (float*)d_out;

    // d_out scratch (consumed before groupnorm rewrites d_out):
    //   msgb bf16 (67.1 MB) | Abuf fp32 (16.8 MB) | Bc fp32 (16.8 MB)
    u16*   msgb = (u16*)out;
    float* Abuf = out + 16777216;
    float* Bc   = out + 16777216 + 4194304;

    // d_ws: Wb 2 MB (Wq|Wk|Wv|Wo bf16) + qkv 201.3 MB (65536 x 1536).
    // h_mfma overwrites qkv's q-slot with h; EPI gemm writes bf16 res into
    // qkv's k-slot (dead after kv_outer_mfma).
    u16* Wb   = (u16*)d_ws;
    u16* qkv  = Wb + 4 * 262144;
    u16* resB = qkv + 512;    // res bf16, stride 1536

    convert_weights<<<dim3(128, 4), 256, 0, stream>>>(Wq, Wk, Wv, Wo, Wb);
    convert_bf16<<<16384, 256, 0, stream>>>(msg, msgb, 4194304);

    // fused QKV GEMM: A=msgb (65536x512), B=[Wq;Wk;Wv] (1536x512) -> qkv
    // 512 row-tiles x 12 col-tiles = 6144 blocks (%8==0)
    gemm4b<0><<<6144, 256, 0, stream>>>(msgb, HD, Wb, qkv, QKVLD, 12, nullptr, nullptr);

    kv_outer_mfma<<<dim3(NHEAD, M_SEG), 256, 0, stream>>>(qkv, Abuf);
    scan_kernel<<<128, 256, 0, stream>>>(Abuf, Bc);
    h_mfma<<<dim3(2, M_SEG), 256, 0, stream>>>(qkv, Bc);

    // output GEMM: A=h (qkv q-slot, lda=1536), B=Wo; res=acc+msgb(bf16)+bias
    // 512 row-tiles x 4 col-tiles = 2048 blocks (%8==0)
    gemm4b<1><<<2048, 256, 0, stream>>>(qkv, QKVLD, Wb + 3 * 262144, resB, QKVLD, 4, msgb, bo);

    zero_row<<<2, 256, 0, stream>>>(out);
    groupnorm_bf16<<<dim3(8, M_SEG), 256, 0, stream>>>(resB, out, gnw, gnb);
}

// Round 11
// 373.111 us; speedup vs baseline: 1.0081x; 1.0032x over previous
//
#include <hip/hip_runtime.h>
#include <math.h>

// Problem constants (fixed by setup_inputs)
#define M_SEG 128
#define S_SEG 512
#define HD 512
#define NHEAD 8
#define DHEAD 64
#define NROWS (M_SEG * S_SEG)   // 65536
#define QKVLD 1536              // fused qkv row stride
#define GAMMA_F 0.96875f
#define SCALE_F 0.125f          // d^-0.5

typedef unsigned short u16;
typedef float f32x4 __attribute__((ext_vector_type(4)));
typedef __bf16 bf16x8 __attribute__((ext_vector_type(8)));
typedef unsigned short ushort8 __attribute__((ext_vector_type(8)));
typedef unsigned short ushort4v __attribute__((ext_vector_type(4)));

__device__ __forceinline__ u16 f2bf(float f) {
    union { float f; unsigned u; } x; x.f = f;
    unsigned r = x.u + 0x7FFFu + ((x.u >> 16) & 1u);   // RNE
    return (u16)(r >> 16);
}
__device__ __forceinline__ float bf2f(u16 v) {
    union { unsigned u; float f; } x; x.u = ((unsigned)v) << 16;
    return x.f;
}

// Full compile-time fence: IR-level (memory clobber) + MIR scheduler (rule #18).
__device__ __forceinline__ void fence_all() {
    asm volatile("" ::: "memory");
    __builtin_amdgcn_sched_barrier(0);
}

// async global->LDS, 16B per lane; LDS dest = wave-uniform base + lane*16
__device__ __forceinline__ void gload16(const u16* g, u16* l) {
    __builtin_amdgcn_global_load_lds(
        (const __attribute__((address_space(1))) void*)g,
        (__attribute__((address_space(3))) void*)l, 16, 0, 0);
}

// ---------------------------------------------------------------------------
// fp32 -> bf16, 8 elems/thread
// ---------------------------------------------------------------------------
__global__ __launch_bounds__(256) void convert_bf16(const float* __restrict__ in,
                                                    u16* __restrict__ outp, int n8)
{
    int idx = blockIdx.x * 256 + threadIdx.x;
    if (idx >= n8) return;
    const float4 a = *reinterpret_cast<const float4*>(&in[(size_t)idx * 8]);
    const float4 b = *reinterpret_cast<const float4*>(&in[(size_t)idx * 8 + 4]);
    ushort8 o;
    o[0] = f2bf(a.x); o[1] = f2bf(a.y); o[2] = f2bf(a.z); o[3] = f2bf(a.w);
    o[4] = f2bf(b.x); o[5] = f2bf(b.y); o[6] = f2bf(b.z); o[7] = f2bf(b.w);
    *reinterpret_cast<ushort8*>(&outp[(size_t)idx * 8]) = o;
}

// 4 weights in one launch (blockIdx.y selects), each 512x512
__global__ __launch_bounds__(256) void convert_weights(const float* __restrict__ w0,
                                                       const float* __restrict__ w1,
                                                       const float* __restrict__ w2,
                                                       const float* __restrict__ w3,
                                                       u16* __restrict__ outp)
{
    const int which = blockIdx.y;
    const float* src = which == 0 ? w0 : which == 1 ? w1 : which == 2 ? w2 : w3;
    u16* dst = outp + (size_t)which * 262144;
    int idx = blockIdx.x * 256 + threadIdx.x;        // 32768 per weight
    const float4 a = *reinterpret_cast<const float4*>(&src[(size_t)idx * 8]);
    const float4 b = *reinterpret_cast<const float4*>(&src[(size_t)idx * 8 + 4]);
    ushort8 o;
    o[0] = f2bf(a.x); o[1] = f2bf(a.y); o[2] = f2bf(a.z); o[3] = f2bf(a.w);
    o[4] = f2bf(b.x); o[5] = f2bf(b.y); o[6] = f2bf(b.z); o[7] = f2bf(b.w);
    *reinterpret_cast<ushort8*>(&dst[(size_t)idx * 8]) = o;
}

// ---------------------------------------------------------------------------
// BK=64 A/B: 128x128 bf16 MFMA GEMM (NT), K=512, 8 K-tiles of 64.
// Variable under test vs R10 (BK=32): sync cadence — ONE {vmcnt+barrier,
// 32 MFMA, barrier} round per 64-K instead of per 32-K (half the barriers
// per FLOP). Everything else held: 4 waves x 64x64, swizzle both-sides,
// counted-vmcnt distance-2 ring, fence_all race guards.
// LDS: 2 bufs x {A 128x64, B 128x64} u16 = 64 KiB -> 2 blocks/CU.
// Staging: 8 gload16/thread/tile; thread t covers rows srow+{0,32,64,96}
// at source k-slot ksl = (t&7)^(srow&7) (srow = t>>3; +32c keeps &7).
// Frag read slot = (ks*4+fkc) ^ (row&7): rows r, r+8 same bank -> 2-way free.
// vmcnt ledger: prologue 16 outstanding; steady wait vmcnt(8) retires the
// current tile (next tile's 8 stay in flight); kt=7 waits vmcnt(0).
// EPI==0: C bf16 (ldc), coalesced via LDS pass.
// EPI==1: res = acc + X(bf16 msgb) + bias -> bf16 at Cv (ldc), 2 half-passes.
// ---------------------------------------------------------------------------
template<int EPI>
__global__ __launch_bounds__(256, 2) void gemm4b(const u16* __restrict__ A, int lda,
                                                 const u16* __restrict__ B,
                                                 u16* __restrict__ Cv, int ldc, int ntile,
                                                 const u16* __restrict__ Xb,
                                                 const float* __restrict__ bias)
{
    __shared__ __align__(16) u16 sm[2][16384];  // [buf][A 8192 | B 8192] = 64 KiB
    const int t    = threadIdx.x;
    const int lane = t & 63;
    const int w    = t >> 6;          // 4 waves
    const int wm   = w >> 1;          // 0..1 -> A 64-row half
    const int wn   = w & 1;           // 0..1 -> B 64-col half

    // XCD-bijective blockIdx swizzle (nwg % 8 == 0 in all uses here)
    const int nwg  = gridDim.x;
    const int cpx  = nwg >> 3;
    const int bid  = blockIdx.x;
    const int sbid = (bid & 7) * cpx + (bid >> 3);
    const int mt = sbid / ntile, nt = sbid % ntile;
    const int rowBase = mt * 128, colBase = nt * 128;

    const int frow = lane & 15, fkc = lane >> 4, orow = (lane >> 4) * 4;

    // staging geometry: srow = t>>3 (0..31), source k-slot inverse-swizzled;
    // (srow + 32c) & 7 == srow & 7, so ksl is call-invariant.
    const int srow = t >> 3;
    const int ksl  = (t & 7) ^ (srow & 7);

    const size_t gA = (size_t)(rowBase + srow) * lda + ksl * 8;
    const size_t gB = (size_t)(colBase + srow) * HD  + ksl * 8;
    const size_t a32 = (size_t)32 * lda;
    const size_t b32 = (size_t)32 * HD;

    f32x4 acc[4][4];
#pragma unroll
    for (int i = 0; i < 4; ++i)
#pragma unroll
        for (int j = 0; j < 4; ++j)
            acc[i][j] = (f32x4){0.f, 0.f, 0.f, 0.f};

#define STAGE(kt, buf)                                                        \
    do {                                                                      \
        const size_t ko_ = (size_t)(kt) * 64;                                 \
        gload16(&A[gA + ko_],           &sm[buf][t * 8]);                     \
        gload16(&A[gA + a32 + ko_],     &sm[buf][2048 + t * 8]);              \
        gload16(&A[gA + 2 * a32 + ko_], &sm[buf][4096 + t * 8]);              \
        gload16(&A[gA + 3 * a32 + ko_], &sm[buf][6144 + t * 8]);              \
        gload16(&B[gB + ko_],           &sm[buf][8192 + t * 8]);              \
        gload16(&B[gB + b32 + ko_],     &sm[buf][10240 + t * 8]);             \
        gload16(&B[gB + 2 * b32 + ko_], &sm[buf][12288 + t * 8]);             \
        gload16(&B[gB + 3 * b32 + ko_], &sm[buf][14336 + t * 8]);             \
    } while (0)

    STAGE(0, 0);
    STAGE(1, 1);

#pragma unroll 1
    for (int kt = 0; kt < 8; ++kt) {
        const int buf = kt & 1;
        if (kt < 7) asm volatile("s_waitcnt vmcnt(8)" ::: "memory");
        else        asm volatile("s_waitcnt vmcnt(0)" ::: "memory");
        __builtin_amdgcn_s_barrier();
        fence_all();

        const u16* Ab = sm[buf];
        const u16* Bb = sm[buf] + 8192;
#pragma unroll
        for (int ks = 0; ks < 2; ++ks) {
            bf16x8 af[4], bfv[4];
#pragma unroll
            for (int mm = 0; mm < 4; ++mm) {
                const int r = wm * 64 + mm * 16 + frow;
                af[mm] = *reinterpret_cast<const bf16x8*>(
                    &Ab[r * 64 + (((ks * 4 + fkc) ^ (r & 7)) << 3)]);
            }
#pragma unroll
            for (int nn = 0; nn < 4; ++nn) {
                const int r = wn * 64 + nn * 16 + frow;
                bfv[nn] = *reinterpret_cast<const bf16x8*>(
                    &Bb[r * 64 + (((ks * 4 + fkc) ^ (r & 7)) << 3)]);
            }
            __builtin_amdgcn_s_setprio(1);
#pragma unroll
            for (int mm = 0; mm < 4; ++mm)
#pragma unroll
                for (int nn = 0; nn < 4; ++nn)
                    acc[mm][nn] = __builtin_amdgcn_mfma_f32_16x16x32_bf16(af[mm], bfv[nn], acc[mm][nn], 0, 0, 0);
            __builtin_amdgcn_s_setprio(0);
        }

        __builtin_amdgcn_s_barrier();   // all waves done reading buf
        fence_all();                    // pin STAGE below the barrier
        if (kt < 6) STAGE(kt + 2, buf);
    }
#undef STAGE

    if (EPI == 0) {
        // acc -> LDS (128x128 u16 = 32 KiB) -> coalesced ushort8 stores
        u16* ldsC = (u16*)sm;
        __syncthreads();
#pragma unroll
        for (int mm = 0; mm < 4; ++mm)
#pragma unroll
            for (int nn = 0; nn < 4; ++nn) {
                const int row0 = wm * 64 + mm * 16 + orow;
                const int col  = wn * 64 + nn * 16 + frow;
#pragma unroll
                for (int r = 0; r < 4; ++r)
                    ldsC[(row0 + r) * 128 + col] = f2bf(acc[mm][nn][r]);
            }
        __syncthreads();
#pragma unroll
        for (int p = 0; p < 8; ++p) {
            const int lin = p * 256 + t;          // 2048 x 16B chunks
            const int row = lin >> 4, c8 = lin & 15;
            *reinterpret_cast<ushort8*>(
                &Cv[(size_t)(rowBase + row) * ldc + colBase + c8 * 8]) =
                *reinterpret_cast<const ushort8*>(&ldsC[row * 128 + c8 * 8]);
        }
    } else {
        // two half-passes of 64 rows: 64x128 f32 = 32 KiB; res=acc+X+bias->bf16
        float* ldsF = (float*)sm;
#pragma unroll
        for (int half = 0; half < 2; ++half) {
            __syncthreads();
            if (wm == half) {
#pragma unroll
                for (int mm = 0; mm < 4; ++mm)
#pragma unroll
                    for (int nn = 0; nn < 4; ++nn) {
                        const int row0 = mm * 16 + orow;          // 0..63 local
                        const int col  = wn * 64 + nn * 16 + frow;
#pragma unroll
                        for (int r = 0; r < 4; ++r)
                            ldsF[(row0 + r) * 128 + col] = acc[mm][nn][r];
                    }
            }
            __syncthreads();
#pragma unroll
            for (int p = 0; p < 8; ++p) {
                const int lin = p * 256 + t;      // 2048 float4 chunks
                const int row = lin >> 5, c4 = lin & 31;
                const int grow = rowBase + half * 64 + row;
                float4 a = *reinterpret_cast<const float4*>(&ldsF[row * 128 + c4 * 4]);
                ushort4v x4 = *reinterpret_cast<const ushort4v*>(
                    &Xb[(size_t)grow * HD + colBase + c4 * 4]);
                float4 b = *reinterpret_cast<const float4*>(&bias[colBase + c4 * 4]);
                ushort4v o;
                o[0] = f2bf(a.x + bf2f(x4[0]) + b.x);
                o[1] = f2bf(a.y + bf2f(x4[1]) + b.y);
                o[2] = f2bf(a.z + bf2f(x4[2]) + b.z);
                o[3] = f2bf(a.w + bf2f(x4[3]) + b.w);
                *reinterpret_cast<ushort4v*>(
                    &Cv[(size_t)grow * ldc + colBase + c4 * 4]) = o;
            }
        }
    }
}

// ---------------------------------------------------------------------------
// MFMA KtV: A[m,h,d,e] = sum_s k[m,s,d] * v[m,s,e].  Race-safe (fence_all
// after each end-of-compute barrier; single-buffered kT/vT).
// ---------------------------------------------------------------------------
__global__ __launch_bounds__(256) void kv_outer_mfma(const u16* __restrict__ qkv,
                                                     float* __restrict__ Abuf)
{
    __shared__ __align__(16) u16 kT[2048];
    __shared__ __align__(16) u16 vT[2048];
    const int t    = threadIdx.x;
    const int lane = t & 63;
    const int w    = t >> 6;
    const int hh   = blockIdx.x;
    const int m    = blockIdx.y;
    const int sl   = t & 31;
    const int dg   = (t >> 5) * 8;
    const int frow = lane & 15, fkc = lane >> 4, orow = (lane >> 4) * 4;
    const size_t gbase = (size_t)(m * S_SEG) * QKVLD + 512 + hh * DHEAD + dg;

    f32x4 acc[4];
#pragma unroll
    for (int i = 0; i < 4; ++i) acc[i] = (f32x4){0.f, 0.f, 0.f, 0.f};

    ushort8 ka, va, kb, vb;

#define LOADC(c, K8, V8)                                                      \
    do {                                                                      \
        size_t g_ = gbase + (size_t)((c) * 32 + sl) * QKVLD;                  \
        K8 = *reinterpret_cast<const ushort8*>(&qkv[g_]);                     \
        V8 = *reinterpret_cast<const ushort8*>(&qkv[g_ + 512]);               \
    } while (0)
#define WRTC(K8, V8)                                                          \
    do {                                                                      \
        _Pragma("unroll")                                                     \
        for (int j = 0; j < 8; ++j) {                                         \
            const int d_ = dg + j;                                            \
            const int a_ = d_ * 32 + ((((sl >> 3) ^ ((d_ >> 1) & 3))) << 3) + (sl & 7); \
            kT[a_] = K8[j];                                                   \
            vT[a_] = V8[j];                                                   \
        }                                                                     \
    } while (0)
#define CMPC()                                                                \
    do {                                                                      \
        bf16x8 kf[4], vf;                                                     \
        _Pragma("unroll")                                                     \
        for (int mf = 0; mf < 4; ++mf) {                                      \
            const int d_ = mf * 16 + frow;                                    \
            kf[mf] = *reinterpret_cast<const bf16x8*>(                        \
                &kT[d_ * 32 + ((fkc ^ ((d_ >> 1) & 3)) << 3)]);               \
        }                                                                     \
        const int e_ = w * 16 + frow;                                         \
        vf = *reinterpret_cast<const bf16x8*>(                                \
            &vT[e_ * 32 + ((fkc ^ ((e_ >> 1) & 3)) << 3)]);                   \
        _Pragma("unroll")                                                     \
        for (int mf = 0; mf < 4; ++mf)                                        \
            acc[mf] = __builtin_amdgcn_mfma_f32_16x16x32_bf16(kf[mf], vf, acc[mf], 0, 0, 0); \
    } while (0)

    LOADC(0, ka, va);
#pragma unroll 1
    for (int cc = 0; cc < 16; cc += 2) {
        WRTC(ka, va);
        LOADC(cc + 1, kb, vb);
        asm volatile("s_waitcnt lgkmcnt(0)" ::: "memory");
        __builtin_amdgcn_s_barrier();
        __builtin_amdgcn_sched_barrier(0);
        CMPC();
        __builtin_amdgcn_s_barrier();
        fence_all();

        WRTC(kb, vb);
        if (cc + 2 < 16) LOADC(cc + 2, ka, va);
        asm volatile("s_waitcnt lgkmcnt(0)" ::: "memory");
        __builtin_amdgcn_s_barrier();
        __builtin_amdgcn_sched_barrier(0);
        CMPC();
        __builtin_amdgcn_s_barrier();
        fence_all();
    }
#undef LOADC
#undef WRTC
#undef CMPC

    const size_t hb = (size_t)(m * NHEAD + hh) * DHEAD * DHEAD;
#pragma unroll
    for (int mf = 0; mf < 4; ++mf)
#pragma unroll
        for (int r = 0; r < 4; ++r)
            Abuf[hb + (size_t)(mf * 16 + orow + r) * DHEAD + w * 16 + frow] = acc[mf][r];
}

// ---------------------------------------------------------------------------
// r_m = A_m + decay*r_{m-1} ;  Bc_m = scale*A_m + gamma^{m+1} * r_m  (fp32)
// ---------------------------------------------------------------------------
__global__ __launch_bounds__(256) void scan_kernel(const float* __restrict__ Abuf,
                                                   float* __restrict__ Bc)
{
    const int tid = blockIdx.x * 256 + threadIdx.x;   // 0..32767
    const float decay = powf(GAMMA_F, (float)S_SEG);
    float r = 0.0f;
    float g = 1.0f;
    for (int m = 0; m < M_SEG; ++m) {
        float a = Abuf[(size_t)m * 32768 + tid];
        r = fmaf(decay, r, a);
        g *= GAMMA_F;
        Bc[(size_t)m * 32768 + tid] = fmaf(g, r, SCALE_F * a);
    }
}

// ---------------------------------------------------------------------------
// h = relu(q @ Bc) IN PLACE into qkv's q-slot (plain bf16 Bc, R10-proven)
// ---------------------------------------------------------------------------
__global__ __launch_bounds__(256) void h_mfma(u16* __restrict__ qkv,
                                              const float* __restrict__ Bc)
{
    __shared__ __align__(16) u16 BT[64 * 72];    // Bc^T [e][d], pad 72
    const int t    = threadIdx.x;
    const int lane = t & 63;
    const int w    = t >> 6;
    const int m    = blockIdx.y;
    const int sBase = blockIdx.x * 256 + w * 64;
    const int frow = lane & 15;
    const int fkc  = lane >> 4;

    for (int hh = 0; hh < NHEAD; ++hh) {
#pragma unroll
        for (int i = 0; i < 4; ++i) {
            int idx = t + i * 256;               // 1024 float4s
            int d = idx >> 4, e4 = idx & 15;
            float4 v = *reinterpret_cast<const float4*>(
                &Bc[((size_t)(m * NHEAD + hh) * DHEAD + d) * DHEAD + e4 * 4]);
            BT[(e4 * 4 + 0) * 72 + d] = f2bf(v.x);
            BT[(e4 * 4 + 1) * 72 + d] = f2bf(v.y);
            BT[(e4 * 4 + 2) * 72 + d] = f2bf(v.z);
            BT[(e4 * 4 + 3) * 72 + d] = f2bf(v.w);
        }
        __syncthreads();

        f32x4 acc[4][4];
#pragma unroll
        for (int i = 0; i < 4; ++i)
#pragma unroll
            for (int j = 0; j < 4; ++j)
                acc[i][j] = (f32x4){0.f, 0.f, 0.f, 0.f};

#pragma unroll
        for (int ks = 0; ks < 2; ++ks) {
            bf16x8 af[4], bfr[4];
#pragma unroll
            for (int mm = 0; mm < 4; ++mm) {
                const int grow = m * S_SEG + sBase + mm * 16 + frow;
                af[mm] = *reinterpret_cast<const bf16x8*>(
                    &qkv[(size_t)grow * QKVLD + hh * DHEAD + ks * 32 + fkc * 8]);
                const int e = mm * 16 + frow;
                bfr[mm] = *reinterpret_cast<const bf16x8*>(&BT[e * 72 + ks * 32 + fkc * 8]);
            }
#pragma unroll
            for (int mm = 0; mm < 4; ++mm)
#pragma unroll
                for (int nn = 0; nn < 4; ++nn)
                    acc[mm][nn] = __builtin_amdgcn_mfma_f32_16x16x32_bf16(af[mm], bfr[nn], acc[mm][nn], 0, 0, 0);
        }

        const int orow = (lane >> 4) * 4;
#pragma unroll
        for (int mm = 0; mm < 4; ++mm)
#pragma unroll
            for (int nn = 0; nn < 4; ++nn) {
                const int col  = hh * DHEAD + nn * 16 + frow;
                const int row0 = m * S_SEG + sBase + mm * 16 + orow;
#pragma unroll
                for (int r = 0; r < 4; ++r)
                    qkv[(size_t)(row0 + r) * QKVLD + col] = f2bf(fmaxf(acc[mm][nn][r], 0.f));
            }
        __syncthreads();
    }
}

// ---------------------------------------------------------------------------
// GroupNorm from bf16 res (qkv k-slot, stride 1536) -> fp32 d_out rows 1..N
// ---------------------------------------------------------------------------
__global__ __launch_bounds__(256) void groupnorm_bf16(const u16* __restrict__ res,
                                                      float* __restrict__ out,
                                                      const float* __restrict__ gn_w,
                                                      const float* __restrict__ gn_b)
{
    const int g = blockIdx.x;
    const int m = blockIdx.y;
    const int t = threadIdx.x;
    const u16* base = res + (size_t)(m * S_SEG) * QKVLD + g * DHEAD;

    float sum = 0.0f, sq = 0.0f;
    for (int idx = t; idx < 4096; idx += 256) {      // 512 rows x 8 ushort8
        int s = idx >> 3, c8 = idx & 7;
        ushort8 v = *reinterpret_cast<const ushort8*>(&base[(size_t)s * QKVLD + c8 * 8]);
#pragma unroll
        for (int j = 0; j < 8; ++j) {
            float f = bf2f(v[j]);
            sum += f; sq += f * f;
        }
    }
    __shared__ float rs[256], rq[256];
    rs[t] = sum; rq[t] = sq;
    __syncthreads();
    for (int off = 128; off > 0; off >>= 1) {
        if (t < off) { rs[t] += rs[t + off]; rq[t] += rq[t + off]; }
        __syncthreads();
    }
    __shared__ float smean, sinv;
    if (t == 0) {
        float mean = rs[0] * (1.0f / 32768.0f);
        float var  = rq[0] * (1.0f / 32768.0f) - mean * mean;
        smean = mean;
        sinv  = rsqrtf(var + 1e-5f);
    }
    __syncthreads();
    const float mean = smean, inv = sinv;

    for (int idx = t; idx < 4096; idx += 256) {
        int s = idx >> 3, c8 = idx & 7;
        ushort8 v = *reinterpret_cast<const ushort8*>(&base[(size_t)s * QKVLD + c8 * 8]);
        float o[8];
#pragma unroll
        for (int j = 0; j < 8; ++j) {
            float wj = gn_w[g * DHEAD + c8 * 8 + j];
            float bj = gn_b[g * DHEAD + c8 * 8 + j];
            o[j] = (bf2f(v[j]) - mean) * inv * wj + bj;
        }
        float* dst = &out[(size_t)(1 + m * S_SEG + s) * HD + g * DHEAD + c8 * 8];
        *reinterpret_cast<float4*>(dst)     = make_float4(o[0], o[1], o[2], o[3]);
        *reinterpret_cast<float4*>(dst + 4) = make_float4(o[4], o[5], o[6], o[7]);
    }
}

__global__ void zero_row(float* __restrict__ out)
{
    int i = blockIdx.x * 256 + threadIdx.x;
    if (i < HD) out[i] = 0.0f;
}

// ---------------------------------------------------------------------------
extern "C" void kernel_launch(void* const* d_in, const int* in_sizes, int n_in,
                              void* d_out, int out_size, void* d_ws, size_t ws_size,
                              hipStream_t stream)
{
    const float* msg = (const float*)d_in[0];
    const float* Wq  = (const float*)d_in[1];
    const float* Wk  = (const float*)d_in[2];
    const float* Wv  = (const float*)d_in[3];
    const float* Wo  = (const float*)d_in[4];
    const float* bo  = (const float*)d_in[5];
    const float* gnw = (const float*)d_in[6];
    const float* gnb = (const float*)d_in[7];
    float* out = (float*)d_out;

    // d_out scratch (consumed before groupnorm rewrites d_out):
    //   msgb bf16 (67.1 MB) | Abuf fp32 (16.8 MB) | Bc fp32 (16.8 MB)
    u16*   msgb = (u16*)out;
    float* Abuf = out + 16777216;
    float* Bc   = out + 16777216 + 4194304;

    // d_ws: Wb 2 MB (Wq|Wk|Wv|Wo bf16) + qkv 201.3 MB (65536 x 1536).
    // h_mfma overwrites qkv's q-slot with h; EPI gemm writes bf16 res into
    // qkv's k-slot (dead after kv_outer_mfma).
    u16* Wb   = (u16*)d_ws;
    u16* qkv  = Wb + 4 * 262144;
    u16* resB = qkv + 512;    // res bf16, stride 1536

    convert_weights<<<dim3(128, 4), 256, 0, stream>>>(Wq, Wk, Wv, Wo, Wb);
    convert_bf16<<<16384, 256, 0, stream>>>(msg, msgb, 4194304);

    // fused QKV GEMM: A=msgb (65536x512), B=[Wq;Wk;Wv] (1536x512) -> qkv
    // 512 row-tiles x 12 col-tiles = 6144 blocks (%8==0)
    gemm4b<0><<<6144, 256, 0, stream>>>(msgb, HD, Wb, qkv, QKVLD, 12, nullptr, nullptr);

    kv_outer_mfma<<<dim3(NHEAD, M_SEG), 256, 0, stream>>>(qkv, Abuf);
    scan_kernel<<<128, 256, 0, stream>>>(Abuf, Bc);
    h_mfma<<<dim3(2, M_SEG), 256, 0, stream>>>(qkv, Bc);

    // output GEMM: A=h (qkv q-slot, lda=1536), B=Wo; res=acc+msgb(bf16)+bias
    // 512 row-tiles x 4 col-tiles = 2048 blocks (%8==0)
    gemm4b<1><<<2048, 256, 0, stream>>>(qkv, QKVLD, Wb + 3 * 262144, resB, QKVLD, 4, msgb, bo);

    zero_row<<<2, 256, 0, stream>>>(out);
    groupnorm_bf16<<<dim3(8, M_SEG), 256, 0, stream>>>(resB, out, gnw, gnb);
}

// Round 12
// 360.226 us; speedup vs baseline: 1.0441x; 1.0358x over previous
//
#include <hip/hip_runtime.h>
#include <math.h>

// Problem constants (fixed by setup_inputs)
#define M_SEG 128
#define S_SEG 512
#define HD 512
#define NHEAD 8
#define DHEAD 64
#define NROWS (M_SEG * S_SEG)   // 65536
#define QKVLD 1536              // fused qkv row stride
#define GAMMA_F 0.96875f
#define SCALE_F 0.125f          // d^-0.5

typedef unsigned short u16;
typedef float f32x4 __attribute__((ext_vector_type(4)));
typedef __bf16 bf16x8 __attribute__((ext_vector_type(8)));
typedef unsigned short ushort8 __attribute__((ext_vector_type(8)));
typedef unsigned short ushort4v __attribute__((ext_vector_type(4)));

__device__ __forceinline__ u16 f2bf(float f) {
    union { float f; unsigned u; } x; x.f = f;
    unsigned r = x.u + 0x7FFFu + ((x.u >> 16) & 1u);   // RNE
    return (u16)(r >> 16);
}
__device__ __forceinline__ float bf2f(u16 v) {
    union { unsigned u; float f; } x; x.u = ((unsigned)v) << 16;
    return x.f;
}

// Full compile-time fence: IR-level (memory clobber) + MIR scheduler (rule #18).
__device__ __forceinline__ void fence_all() {
    asm volatile("" ::: "memory");
    __builtin_amdgcn_sched_barrier(0);
}

// async global->LDS, 16B per lane; LDS dest = wave-uniform base + lane*16
__device__ __forceinline__ void gload16(const u16* g, u16* l) {
    __builtin_amdgcn_global_load_lds(
        (const __attribute__((address_space(1))) void*)g,
        (__attribute__((address_space(3))) void*)l, 16, 0, 0);
}

// ---------------------------------------------------------------------------
// One-shot fp32 -> bf16 for msg (16384 blocks) + 4 weights (512 blocks).
// ---------------------------------------------------------------------------
__global__ __launch_bounds__(256) void convert_all(const float* __restrict__ msg,
                                                   const float* __restrict__ w0,
                                                   const float* __restrict__ w1,
                                                   const float* __restrict__ w2,
                                                   const float* __restrict__ w3,
                                                   u16* __restrict__ msgb,
                                                   u16* __restrict__ Wb)
{
    const int b = blockIdx.x;
    const float* src;
    u16* dst;
    int idx;
    if (b < 16384) {
        src = msg; dst = msgb; idx = b * 256 + threadIdx.x;
    } else {
        const int wb = b - 16384;        // 0..511, 128 blocks per weight
        const int which = wb >> 7;
        src = which == 0 ? w0 : which == 1 ? w1 : which == 2 ? w2 : w3;
        dst = Wb + (size_t)which * 262144;
        idx = (wb & 127) * 256 + threadIdx.x;
    }
    const float4 a = *reinterpret_cast<const float4*>(&src[(size_t)idx * 8]);
    const float4 c = *reinterpret_cast<const float4*>(&src[(size_t)idx * 8 + 4]);
    ushort8 o;
    o[0] = f2bf(a.x); o[1] = f2bf(a.y); o[2] = f2bf(a.z); o[3] = f2bf(a.w);
    o[4] = f2bf(c.x); o[5] = f2bf(c.y); o[6] = f2bf(c.z); o[7] = f2bf(c.w);
    *reinterpret_cast<ushort8*>(&dst[(size_t)idx * 8]) = o;
}

// ---------------------------------------------------------------------------
// FROZEN GEMM (R10-proven best of 6 structural A/Bs, all 136±4 µs):
// 128x128 bf16 MFMA (NT), K=512, BK=32, 16 K-tiles, 4 waves, 2-buffer
// 32 KiB LDS, ~4 blocks/CU. Race-safe fence_all ring; counted vmcnt(4);
// swizzle both-sides. ~757 TF at this shape = family envelope (m102 curve).
// EPI==0: C bf16 (ldc), coalesced LDS pass.
// EPI==1: res = acc + X(bf16 msgb) + bias -> bf16 at Cv (ldc), 2 half-passes.
// ---------------------------------------------------------------------------
template<int EPI>
__global__ __launch_bounds__(256, 4) void gemm4b(const u16* __restrict__ A, int lda,
                                                 const u16* __restrict__ B,
                                                 u16* __restrict__ Cv, int ldc, int ntile,
                                                 const u16* __restrict__ Xb,
                                                 const float* __restrict__ bias)
{
    __shared__ __align__(16) u16 sm[2][8192];   // [buf][A 4096 | B 4096] = 32 KiB
    const int t    = threadIdx.x;
    const int lane = t & 63;
    const int w    = t >> 6;          // 4 waves
    const int wm   = w >> 1;          // 0..1 -> A 64-row half
    const int wn   = w & 1;           // 0..1 -> B 64-col half

    // XCD-bijective blockIdx swizzle (nwg % 8 == 0 in all uses here)
    const int nwg  = gridDim.x;
    const int cpx  = nwg >> 3;
    const int bid  = blockIdx.x;
    const int sbid = (bid & 7) * cpx + (bid >> 3);
    const int mt = sbid / ntile, nt = sbid % ntile;
    const int rowBase = mt * 128, colBase = nt * 128;

    const int frow = lane & 15, fkc = lane >> 4, orow = (lane >> 4) * 4;

    // staging: chunk t; rows sr0 (0..63) and sr0+64; source k-slot inverse-swz
    const int sr0 = t >> 2;
    const int ksl = (t & 3) ^ ((sr0 >> 1) & 3);    // (sr0+64)>>1 same &3

    const size_t gA0 = (size_t)(rowBase + sr0)      * lda + ksl * 8;
    const size_t gA1 = (size_t)(rowBase + sr0 + 64) * lda + ksl * 8;
    const size_t gB0 = (size_t)(colBase + sr0)      * HD  + ksl * 8;
    const size_t gB1 = (size_t)(colBase + sr0 + 64) * HD  + ksl * 8;

    f32x4 acc[4][4];
#pragma unroll
    for (int i = 0; i < 4; ++i)
#pragma unroll
        for (int j = 0; j < 4; ++j)
            acc[i][j] = (f32x4){0.f, 0.f, 0.f, 0.f};

#define STAGE(kt, buf)                                                        \
    do {                                                                      \
        gload16(&A[gA0 + (kt) * 32], &sm[buf][t * 8]);                        \
        gload16(&A[gA1 + (kt) * 32], &sm[buf][2048 + t * 8]);                 \
        gload16(&B[gB0 + (kt) * 32], &sm[buf][4096 + t * 8]);                 \
        gload16(&B[gB1 + (kt) * 32], &sm[buf][6144 + t * 8]);                 \
    } while (0)

    STAGE(0, 0);
    STAGE(1, 1);

#pragma unroll 1
    for (int kt = 0; kt < 16; ++kt) {
        const int buf = kt & 1;
        if (kt < 15) asm volatile("s_waitcnt vmcnt(4)" ::: "memory");
        else         asm volatile("s_waitcnt vmcnt(0)" ::: "memory");
        __builtin_amdgcn_s_barrier();
        fence_all();

        const u16* Ab = sm[buf];
        const u16* Bb = sm[buf] + 4096;
        bf16x8 af[4], bfv[4];
#pragma unroll
        for (int mm = 0; mm < 4; ++mm) {
            const int r = wm * 64 + mm * 16 + frow;
            af[mm] = *reinterpret_cast<const bf16x8*>(
                &Ab[r * 32 + ((fkc ^ ((r >> 1) & 3)) << 3)]);
        }
#pragma unroll
        for (int nn = 0; nn < 4; ++nn) {
            const int r = wn * 64 + nn * 16 + frow;
            bfv[nn] = *reinterpret_cast<const bf16x8*>(
                &Bb[r * 32 + ((fkc ^ ((r >> 1) & 3)) << 3)]);
        }
        __builtin_amdgcn_s_setprio(1);
#pragma unroll
        for (int mm = 0; mm < 4; ++mm)
#pragma unroll
            for (int nn = 0; nn < 4; ++nn)
                acc[mm][nn] = __builtin_amdgcn_mfma_f32_16x16x32_bf16(af[mm], bfv[nn], acc[mm][nn], 0, 0, 0);
        __builtin_amdgcn_s_setprio(0);

        __builtin_amdgcn_s_barrier();   // all waves done reading buf
        fence_all();                    // pin STAGE below the barrier
        if (kt < 14) STAGE(kt + 2, buf);
    }
#undef STAGE

    if (EPI == 0) {
        // acc -> LDS (128x128 u16 = 32 KiB) -> coalesced ushort8 stores
        u16* ldsC = (u16*)sm;
#pragma unroll
        for (int mm = 0; mm < 4; ++mm)
#pragma unroll
            for (int nn = 0; nn < 4; ++nn) {
                const int row0 = wm * 64 + mm * 16 + orow;
                const int col  = wn * 64 + nn * 16 + frow;
#pragma unroll
                for (int r = 0; r < 4; ++r)
                    ldsC[(row0 + r) * 128 + col] = f2bf(acc[mm][nn][r]);
            }
        __syncthreads();
#pragma unroll
        for (int p = 0; p < 8; ++p) {
            const int lin = p * 256 + t;          // 2048 x 16B chunks
            const int row = lin >> 4, c8 = lin & 15;
            *reinterpret_cast<ushort8*>(
                &Cv[(size_t)(rowBase + row) * ldc + colBase + c8 * 8]) =
                *reinterpret_cast<const ushort8*>(&ldsC[row * 128 + c8 * 8]);
        }
    } else {
        // two half-passes of 64 rows: 64x128 f32 = 32 KiB; res=acc+X+bias->bf16
        float* ldsF = (float*)sm;
#pragma unroll
        for (int half = 0; half < 2; ++half) {
            __syncthreads();
            if (wm == half) {
#pragma unroll
                for (int mm = 0; mm < 4; ++mm)
#pragma unroll
                    for (int nn = 0; nn < 4; ++nn) {
                        const int row0 = mm * 16 + orow;          // 0..63 local
                        const int col  = wn * 64 + nn * 16 + frow;
#pragma unroll
                        for (int r = 0; r < 4; ++r)
                            ldsF[(row0 + r) * 128 + col] = acc[mm][nn][r];
                    }
            }
            __syncthreads();
#pragma unroll
            for (int p = 0; p < 8; ++p) {
                const int lin = p * 256 + t;      // 2048 float4 chunks
                const int row = lin >> 5, c4 = lin & 31;
                const int grow = rowBase + half * 64 + row;
                float4 a = *reinterpret_cast<const float4*>(&ldsF[row * 128 + c4 * 4]);
                ushort4v x4 = *reinterpret_cast<const ushort4v*>(
                    &Xb[(size_t)grow * HD + colBase + c4 * 4]);
                float4 b = *reinterpret_cast<const float4*>(&bias[colBase + c4 * 4]);
                ushort4v o;
                o[0] = f2bf(a.x + bf2f(x4[0]) + b.x);
                o[1] = f2bf(a.y + bf2f(x4[1]) + b.y);
                o[2] = f2bf(a.z + bf2f(x4[2]) + b.z);
                o[3] = f2bf(a.w + bf2f(x4[3]) + b.w);
                *reinterpret_cast<ushort4v*>(
                    &Cv[(size_t)grow * ldc + colBase + c4 * 4]) = o;
            }
        }
    }
}

// ---------------------------------------------------------------------------
// MFMA KtV: A[m,h,d,e] = sum_s k[m,s,d] * v[m,s,e].  Race-safe (fence_all
// after each end-of-compute barrier; single-buffered kT/vT).
// ---------------------------------------------------------------------------
__global__ __launch_bounds__(256) void kv_outer_mfma(const u16* __restrict__ qkv,
                                                     float* __restrict__ Abuf)
{
    __shared__ __align__(16) u16 kT[2048];
    __shared__ __align__(16) u16 vT[2048];
    const int t    = threadIdx.x;
    const int lane = t & 63;
    const int w    = t >> 6;
    const int hh   = blockIdx.x;
    const int m    = blockIdx.y;
    const int sl   = t & 31;
    const int dg   = (t >> 5) * 8;
    const int frow = lane & 15, fkc = lane >> 4, orow = (lane >> 4) * 4;
    const size_t gbase = (size_t)(m * S_SEG) * QKVLD + 512 + hh * DHEAD + dg;

    f32x4 acc[4];
#pragma unroll
    for (int i = 0; i < 4; ++i) acc[i] = (f32x4){0.f, 0.f, 0.f, 0.f};

    ushort8 ka, va, kb, vb;

#define LOADC(c, K8, V8)                                                      \
    do {                                                                      \
        size_t g_ = gbase + (size_t)((c) * 32 + sl) * QKVLD;                  \
        K8 = *reinterpret_cast<const ushort8*>(&qkv[g_]);                     \
        V8 = *reinterpret_cast<const ushort8*>(&qkv[g_ + 512]);               \
    } while (0)
#define WRTC(K8, V8)                                                          \
    do {                                                                      \
        _Pragma("unroll")                                                     \
        for (int j = 0; j < 8; ++j) {                                         \
            const int d_ = dg + j;                                            \
            const int a_ = d_ * 32 + ((((sl >> 3) ^ ((d_ >> 1) & 3))) << 3) + (sl & 7); \
            kT[a_] = K8[j];                                                   \
            vT[a_] = V8[j];                                                   \
        }                                                                     \
    } while (0)
#define CMPC()                                                                \
    do {                                                                      \
        bf16x8 kf[4], vf;                                                     \
        _Pragma("unroll")                                                     \
        for (int mf = 0; mf < 4; ++mf) {                                      \
            const int d_ = mf * 16 + frow;                                    \
            kf[mf] = *reinterpret_cast<const bf16x8*>(                        \
                &kT[d_ * 32 + ((fkc ^ ((d_ >> 1) & 3)) << 3)]);               \
        }                                                                     \
        const int e_ = w * 16 + frow;                                         \
        vf = *reinterpret_cast<const bf16x8*>(                                \
            &vT[e_ * 32 + ((fkc ^ ((e_ >> 1) & 3)) << 3)]);                   \
        _Pragma("unroll")                                                     \
        for (int mf = 0; mf < 4; ++mf)                                        \
            acc[mf] = __builtin_amdgcn_mfma_f32_16x16x32_bf16(kf[mf], vf, acc[mf], 0, 0, 0); \
    } while (0)

    LOADC(0, ka, va);
#pragma unroll 1
    for (int cc = 0; cc < 16; cc += 2) {
        WRTC(ka, va);
        LOADC(cc + 1, kb, vb);
        asm volatile("s_waitcnt lgkmcnt(0)" ::: "memory");
        __builtin_amdgcn_s_barrier();
        __builtin_amdgcn_sched_barrier(0);
        CMPC();
        __builtin_amdgcn_s_barrier();
        fence_all();

        WRTC(kb, vb);
        if (cc + 2 < 16) LOADC(cc + 2, ka, va);
        asm volatile("s_waitcnt lgkmcnt(0)" ::: "memory");
        __builtin_amdgcn_s_barrier();
        __builtin_amdgcn_sched_barrier(0);
        CMPC();
        __builtin_amdgcn_s_barrier();
        fence_all();
    }
#undef LOADC
#undef WRTC
#undef CMPC

    const size_t hb = (size_t)(m * NHEAD + hh) * DHEAD * DHEAD;
#pragma unroll
    for (int mf = 0; mf < 4; ++mf)
#pragma unroll
        for (int r = 0; r < 4; ++r)
            Abuf[hb + (size_t)(mf * 16 + orow + r) * DHEAD + w * 16 + frow] = acc[mf][r];
}

// ---------------------------------------------------------------------------
// r_m = A_m + decay*r_{m-1} ;  Bc_m = scale*A_m + gamma^{m+1} * r_m  (fp32)
// ---------------------------------------------------------------------------
__global__ __launch_bounds__(256) void scan_kernel(const float* __restrict__ Abuf,
                                                   float* __restrict__ Bc)
{
    const int tid = blockIdx.x * 256 + threadIdx.x;   // 0..32767
    const float decay = powf(GAMMA_F, (float)S_SEG);
    float r = 0.0f;
    float g = 1.0f;
    for (int m = 0; m < M_SEG; ++m) {
        float a = Abuf[(size_t)m * 32768 + tid];
        r = fmaf(decay, r, a);
        g *= GAMMA_F;
        Bc[(size_t)m * 32768 + tid] = fmaf(g, r, SCALE_F * a);
    }
}

// ---------------------------------------------------------------------------
// h = relu(q @ Bc) IN PLACE into qkv's q-slot. R12: C-writes now staged via
// a 34 KiB LDS tile (pad 68) and emitted as 128B-contiguous ushort8 rows —
// removes the 2x write-amplified 2B-granule scatter (R2-measured signature).
// ---------------------------------------------------------------------------
__global__ __launch_bounds__(256) void h_mfma(u16* __restrict__ qkv,
                                              const float* __restrict__ Bc)
{
    __shared__ __align__(16) u16 BT[64 * 72];    // Bc^T [e][d], pad 72
    __shared__ __align__(16) u16 hC[256 * 68];   // C-stage, pad 68
    const int t    = threadIdx.x;
    const int lane = t & 63;
    const int w    = t >> 6;
    const int m    = blockIdx.y;
    const int bRow0 = blockIdx.x * 256;          // block-local row base in segment
    const int sBase = bRow0 + w * 64;
    const int frow = lane & 15;
    const int fkc  = lane >> 4;
    const int orow = (lane >> 4) * 4;

    for (int hh = 0; hh < NHEAD; ++hh) {
#pragma unroll
        for (int i = 0; i < 4; ++i) {
            int idx = t + i * 256;               // 1024 float4s
            int d = idx >> 4, e4 = idx & 15;
            float4 v = *reinterpret_cast<const float4*>(
                &Bc[((size_t)(m * NHEAD + hh) * DHEAD + d) * DHEAD + e4 * 4]);
            BT[(e4 * 4 + 0) * 72 + d] = f2bf(v.x);
            BT[(e4 * 4 + 1) * 72 + d] = f2bf(v.y);
            BT[(e4 * 4 + 2) * 72 + d] = f2bf(v.z);
            BT[(e4 * 4 + 3) * 72 + d] = f2bf(v.w);
        }
        __syncthreads();

        f32x4 acc[4][4];
#pragma unroll
        for (int i = 0; i < 4; ++i)
#pragma unroll
            for (int j = 0; j < 4; ++j)
                acc[i][j] = (f32x4){0.f, 0.f, 0.f, 0.f};

#pragma unroll
        for (int ks = 0; ks < 2; ++ks) {
            bf16x8 af[4], bfr[4];
#pragma unroll
            for (int mm = 0; mm < 4; ++mm) {
                const int grow = m * S_SEG + sBase + mm * 16 + frow;
                af[mm] = *reinterpret_cast<const bf16x8*>(
                    &qkv[(size_t)grow * QKVLD + hh * DHEAD + ks * 32 + fkc * 8]);
                const int e = mm * 16 + frow;
                bfr[mm] = *reinterpret_cast<const bf16x8*>(&BT[e * 72 + ks * 32 + fkc * 8]);
            }
#pragma unroll
            for (int mm = 0; mm < 4; ++mm)
#pragma unroll
                for (int nn = 0; nn < 4; ++nn)
                    acc[mm][nn] = __builtin_amdgcn_mfma_f32_16x16x32_bf16(af[mm], bfr[nn], acc[mm][nn], 0, 0, 0);
        }

        // stage C tile into LDS (rows local to block: w*64 + mm*16+orow+r)
#pragma unroll
        for (int mm = 0; mm < 4; ++mm)
#pragma unroll
            for (int nn = 0; nn < 4; ++nn) {
                const int rl0 = w * 64 + mm * 16 + orow;
                const int cl  = nn * 16 + frow;
#pragma unroll
                for (int r = 0; r < 4; ++r)
                    hC[(rl0 + r) * 68 + cl] = f2bf(fmaxf(acc[mm][nn][r], 0.f));
            }
        __syncthreads();
        // coalesced copy: 2048 ushort8 chunks, 128B contiguous per row
#pragma unroll
        for (int i = 0; i < 8; ++i) {
            const int lin = i * 256 + t;
            const int row = lin >> 3, c8 = lin & 7;
            *reinterpret_cast<ushort8*>(
                &qkv[(size_t)(m * S_SEG + bRow0 + row) * QKVLD + hh * DHEAD + c8 * 8]) =
                *reinterpret_cast<const ushort8*>(&hC[row * 68 + c8 * 8]);
        }
        __syncthreads();   // protects BT and hC before next head
    }
}

// ---------------------------------------------------------------------------
// GroupNorm, single global read: stage the (512x64) bf16 group tile in
// 64 KiB LDS during the stats pass, normalize from LDS -> fp32 d_out.
// m==0 blocks also zero output row 0 (zero_row merged).
// ---------------------------------------------------------------------------
__global__ __launch_bounds__(256) void groupnorm_bf16(const u16* __restrict__ res,
                                                      float* __restrict__ out,
                                                      const float* __restrict__ gn_w,
                                                      const float* __restrict__ gn_b)
{
    __shared__ __align__(16) u16 hL[512 * 64];   // 64 KiB
    const int g = blockIdx.x;
    const int m = blockIdx.y;
    const int t = threadIdx.x;
    const u16* base = res + (size_t)(m * S_SEG) * QKVLD + g * DHEAD;

    if (m == 0 && t < 64) out[g * DHEAD + t] = 0.0f;   // cached_zero_vector row

    float sum = 0.0f, sq = 0.0f;
    for (int idx = t; idx < 4096; idx += 256) {      // 512 rows x 8 ushort8
        int s = idx >> 3, c8 = idx & 7;
        ushort8 v = *reinterpret_cast<const ushort8*>(&base[(size_t)s * QKVLD + c8 * 8]);
        *reinterpret_cast<ushort8*>(&hL[s * 64 + c8 * 8]) = v;
#pragma unroll
        for (int j = 0; j < 8; ++j) {
            float f = bf2f(v[j]);
            sum += f; sq += f * f;
        }
    }
    __shared__ float rs[256], rq[256];
    rs[t] = sum; rq[t] = sq;
    __syncthreads();
    for (int off = 128; off > 0; off >>= 1) {
        if (t < off) { rs[t] += rs[t + off]; rq[t] += rq[t + off]; }
        __syncthreads();
    }
    __shared__ float smean, sinv;
    if (t == 0) {
        float mean = rs[0] * (1.0f / 32768.0f);
        float var  = rq[0] * (1.0f / 32768.0f) - mean * mean;
        smean = mean;
        sinv  = rsqrtf(var + 1e-5f);
    }
    __syncthreads();
    const float mean = smean, inv = sinv;

    for (int idx = t; idx < 4096; idx += 256) {
        int s = idx >> 3, c8 = idx & 7;
        ushort8 v = *reinterpret_cast<const ushort8*>(&hL[s * 64 + c8 * 8]);
        float o[8];
#pragma unroll
        for (int j = 0; j < 8; ++j) {
            float wj = gn_w[g * DHEAD + c8 * 8 + j];
            float bj = gn_b[g * DHEAD + c8 * 8 + j];
            o[j] = (bf2f(v[j]) - mean) * inv * wj + bj;
        }
        float* dst = &out[(size_t)(1 + m * S_SEG + s) * HD + g * DHEAD + c8 * 8];
        *reinterpret_cast<float4*>(dst)     = make_float4(o[0], o[1], o[2], o[3]);
        *reinterpret_cast<float4*>(dst + 4) = make_float4(o[4], o[5], o[6], o[7]);
    }
}

// ---------------------------------------------------------------------------
extern "C" void kernel_launch(void* const* d_in, const int* in_sizes, int n_in,
                              void* d_out, int out_size, void* d_ws, size_t ws_size,
                              hipStream_t stream)
{
    const float* msg = (const float*)d_in[0];
    const float* Wq  = (const float*)d_in[1];
    const float* Wk  = (const float*)d_in[2];
    const float* Wv  = (const float*)d_in[3];
    const float* Wo  = (const float*)d_in[4];
    const float* bo  = (const float*)d_in[5];
    const float* gnw = (const float*)d_in[6];
    const float* gnb = (const float*)d_in[7];
    float* out = (float*)d_out;

    // d_out scratch (consumed before groupnorm rewrites d_out):
    //   msgb bf16 (67.1 MB) | Abuf fp32 (16.8 MB) | Bc fp32 (16.8 MB)
    u16*   msgb = (u16*)out;
    float* Abuf = out + 16777216;
    float* Bc   = out + 16777216 + 4194304;

    // d_ws: Wb 2 MB (Wq|Wk|Wv|Wo bf16) + qkv 201.3 MB (65536 x 1536).
    // h_mfma overwrites qkv's q-slot with h; EPI gemm writes bf16 res into
    // qkv's k-slot (dead after kv_outer_mfma).
    u16* Wb   = (u16*)d_ws;
    u16* qkv  = Wb + 4 * 262144;
    u16* resB = qkv + 512;    // res bf16, stride 1536

    convert_all<<<16896, 256, 0, stream>>>(msg, Wq, Wk, Wv, Wo, msgb, Wb);

    // fused QKV GEMM: A=msgb (65536x512), B=[Wq;Wk;Wv] (1536x512) -> qkv
    // 512 row-tiles x 12 col-tiles = 6144 blocks (%8==0)
    gemm4b<0><<<6144, 256, 0, stream>>>(msgb, HD, Wb, qkv, QKVLD, 12, nullptr, nullptr);

    kv_outer_mfma<<<dim3(NHEAD, M_SEG), 256, 0, stream>>>(qkv, Abuf);
    scan_kernel<<<128, 256, 0, stream>>>(Abuf, Bc);
    h_mfma<<<dim3(2, M_SEG), 256, 0, stream>>>(qkv, Bc);

    // output GEMM: A=h (qkv q-slot, lda=1536), B=Wo; res=acc+msgb(bf16)+bias
    // 512 row-tiles x 4 col-tiles = 2048 blocks (%8==0)
    gemm4b<1><<<2048, 256, 0, stream>>>(qkv, QKVLD, Wb + 3 * 262144, resB, QKVLD, 4, msgb, bo);

    groupnorm_bf16<<<dim3(8, M_SEG), 256, 0, stream>>>(resB, out, gnw, gnb);
}